// Round 9
// baseline (2605.449 us; speedup 1.0000x reference)
//
#include <hip/hip_runtime.h>
#include <math.h>

typedef unsigned short u16;
typedef unsigned u32;
typedef float f32x4 __attribute__((ext_vector_type(4)));
typedef float f32x2 __attribute__((ext_vector_type(2)));
typedef __bf16 bf16x8 __attribute__((ext_vector_type(8)));
typedef u16 u16x8 __attribute__((ext_vector_type(8)));
typedef u16 u16x4 __attribute__((ext_vector_type(4)));
typedef u32 u32x4 __attribute__((ext_vector_type(4)));

#define L_SEQ 256
#define BSZ 32
#define HID 1024
#define NIN 1024
#define VOC 10000
#define G4 4096
#define MROWS 8192
#define NB 64    // recurrence blocks
#define DPB 16   // h-dims per block
#define SENT 0xFFFFFFFFu

__device__ __forceinline__ u16 f2bf(float f) {
    unsigned u = __float_as_uint(f);
    unsigned r = u + 0x7FFFu + ((u >> 16) & 1u);
    return (u16)(r >> 16);
}
#define BF2F(x) __builtin_bit_cast(float, (u32)((u16)(x)) << 16)

__device__ __forceinline__ float fast_sigm(float x) {
    x = fminf(fmaxf(x, -15.f), 15.f);
    return __builtin_amdgcn_rcpf(1.f + __expf(-x));
}
__device__ __forceinline__ float fast_tanh(float x) {
    x = fminf(fmaxf(x, -15.f), 15.f);
    float t = __expf(2.f * x);
    return (t - 1.f) * __builtin_amdgcn_rcpf(t + 1.f);
}
__device__ __forceinline__ unsigned umax4(u16x8 v) {
    u32x4 c = __builtin_bit_cast(u32x4, v);
    unsigned a = c.x > c.y ? c.x : c.y;
    unsigned b = c.z > c.w ? c.z : c.w;
    return a > b ? a : b;
}

// ---------------- converters ----------------
__global__ __launch_bounds__(256) void cvt_bf16_kernel(const float* __restrict__ in,
                                                       u16* __restrict__ out, int n4) {
    int idx = blockIdx.x * 256 + threadIdx.x;
    if (idx < n4) {
        f32x4 v = *(const f32x4*)(in + (size_t)idx * 4);
        u16x4 o = {f2bf(v.x), f2bf(v.y), f2bf(v.z), f2bf(v.w)};
        *(u16x4*)(out + (size_t)idx * 4) = o;
    }
}

__global__ __launch_bounds__(256) void gather_emb_kernel(const int* __restrict__ ids,
                                                         const float* __restrict__ emb_w,
                                                         u16* __restrict__ out) {
    int m = blockIdx.x;
    int id = ids[m];
    const float* src = emb_w + (size_t)id * NIN;
    u16* dst = out + (size_t)m * NIN;
    int t = threadIdx.x;
    f32x4 v = *(const f32x4*)(src + t * 4);
    u16x4 o = {f2bf(v.x), f2bf(v.y), f2bf(v.z), f2bf(v.w)};
    *(u16x4*)(dst + t * 4) = o;
}

// ---------------- gemm1: gx = emb @ w_ih^T, transposed layout ----------------
// gxT index: (((dblk*L_SEQ + i)*4 + g)*16 + dl)*32 + b   (f32)
__global__ __launch_bounds__(256) void gemm_gxT_kernel(const u16* __restrict__ A,
                                                       const u16* __restrict__ B,
                                                       float* __restrict__ gxT) {
    int m0 = blockIdx.x * 128;
    int n0 = blockIdx.y * 128;
    __shared__ alignas(16) u16 As[128][40];
    __shared__ alignas(16) u16 Bs[128][40];
    int t = threadIdx.x;
    int lane = t & 63, wave = t >> 6;
    int wr = wave >> 1, wc = wave & 1;
    int l15 = lane & 15, l4 = lane >> 4;

    f32x4 acc[4][4];
    f32x4 zv = {0.f, 0.f, 0.f, 0.f};
    for (int mi = 0; mi < 4; ++mi)
        for (int ni = 0; ni < 4; ++ni) acc[mi][ni] = zv;

    for (int k0 = 0; k0 < NIN; k0 += 32) {
        for (int s = 0; s < 2; ++s) {
            int task = t + s * 256;
            int row = task >> 2, kof = (task & 3) * 8;
            *(u16x8*)(&As[row][kof]) = *(const u16x8*)(A + (size_t)(m0 + row) * NIN + k0 + kof);
            *(u16x8*)(&Bs[row][kof]) = *(const u16x8*)(B + (size_t)(n0 + row) * NIN + k0 + kof);
        }
        __syncthreads();
        bf16x8 af[4], bfr[4];
        for (int mi = 0; mi < 4; ++mi)
            af[mi] = __builtin_bit_cast(bf16x8, *(const u16x8*)(&As[wr * 64 + mi * 16 + l15][l4 * 8]));
        for (int ni = 0; ni < 4; ++ni)
            bfr[ni] = __builtin_bit_cast(bf16x8, *(const u16x8*)(&Bs[wc * 64 + ni * 16 + l15][l4 * 8]));
        for (int mi = 0; mi < 4; ++mi)
            for (int ni = 0; ni < 4; ++ni)
                acc[mi][ni] = __builtin_amdgcn_mfma_f32_16x16x32_bf16(af[mi], bfr[ni], acc[mi][ni], 0, 0, 0);
        __syncthreads();
    }
    for (int mi = 0; mi < 4; ++mi)
        for (int ni = 0; ni < 4; ++ni) {
            int n = n0 + wc * 64 + ni * 16 + l15;
            int g = n >> 10, dd = n & 1023;
            int dblk = dd >> 4, dl = dd & 15;
            int mbase = m0 + wr * 64 + mi * 16 + l4 * 4;
            int i = mbase >> 5, bb = mbase & 31;
            size_t idx = ((((size_t)dblk * L_SEQ + i) * 4 + g) * 16 + dl) * 32 + bb;
            *(f32x4*)(&gxT[idx]) = acc[mi][ni];
        }
}

// ---------------- decoder GEMM: C[M][N] = A[M][K] * B[N][K]^T + bias ----------------
__global__ __launch_bounds__(256) void gemm_bt_kernel(const u16* __restrict__ A,
                                                      const u16* __restrict__ B,
                                                      float* __restrict__ C,
                                                      const float* __restrict__ bias,
                                                      int M, int N, int K) {
    int m0 = blockIdx.x * 128;
    int n0 = blockIdx.y * 128;
    __shared__ alignas(16) u16 As[128][40];
    __shared__ alignas(16) u16 Bs[128][40];
    int t = threadIdx.x;
    int lane = t & 63, wave = t >> 6;
    int wr = wave >> 1, wc = wave & 1;
    int l15 = lane & 15, l4 = lane >> 4;

    f32x4 acc[4][4];
    f32x4 zv = {0.f, 0.f, 0.f, 0.f};
    for (int mi = 0; mi < 4; ++mi)
        for (int ni = 0; ni < 4; ++ni) acc[mi][ni] = zv;

    for (int k0 = 0; k0 < K; k0 += 32) {
        for (int s = 0; s < 2; ++s) {
            int task = t + s * 256;
            int row = task >> 2, kof = (task & 3) * 8;
            u16x8 av = *(const u16x8*)(A + (size_t)(m0 + row) * K + k0 + kof);
            *(u16x8*)(&As[row][kof]) = av;
            int brow = n0 + row;
            u16x8 bv = {0, 0, 0, 0, 0, 0, 0, 0};
            if (brow < N) bv = *(const u16x8*)(B + (size_t)brow * K + k0 + kof);
            *(u16x8*)(&Bs[row][kof]) = bv;
        }
        __syncthreads();
        bf16x8 af[4], bfr[4];
        for (int mi = 0; mi < 4; ++mi)
            af[mi] = __builtin_bit_cast(bf16x8, *(const u16x8*)(&As[wr * 64 + mi * 16 + l15][l4 * 8]));
        for (int ni = 0; ni < 4; ++ni)
            bfr[ni] = __builtin_bit_cast(bf16x8, *(const u16x8*)(&Bs[wc * 64 + ni * 16 + l15][l4 * 8]));
        for (int mi = 0; mi < 4; ++mi)
            for (int ni = 0; ni < 4; ++ni)
                acc[mi][ni] = __builtin_amdgcn_mfma_f32_16x16x32_bf16(af[mi], bfr[ni], acc[mi][ni], 0, 0, 0);
        __syncthreads();
    }

    for (int mi = 0; mi < 4; ++mi)
        for (int ni = 0; ni < 4; ++ni) {
            int col = n0 + wc * 64 + ni * 16 + l15;
            if (col < N) {
                float bb = bias ? bias[col] : 0.f;
                int rbase = m0 + wr * 64 + mi * 16 + l4 * 4;
                for (int r = 0; r < 4; ++r)
                    C[(size_t)(rbase + r) * N + col] = acc[mi][ni][r] + bb;
            }
        }
}

// ---------------- persistent LSTM recurrence ----------------
// r8 protocol + (a) gxa prefetched one step ahead, (b) consume-as-arrive MFMA
// inside the poll loop, (c) padded gsm/c_sl (bank-conflict fix).
__global__ __launch_bounds__(256, 1) void lstm_seq_kernel(
    const float* __restrict__ c0, const u16* __restrict__ w_hh_bf,
    const float* __restrict__ gxT, const float* __restrict__ Wv, const float* __restrict__ Uv,
    u16* __restrict__ hb_hist, float* __restrict__ out_tail, float* __restrict__ part_ab) {
    __shared__ alignas(16) u16 Bs[64][1024];  // 128KB w_hh slice, XOR-swizzled 16B chunks
    __shared__ float gsm[4][32][17];          // padded: bank-conflict-free exchange
    __shared__ float c_sl[32][17];

    int blk = blockIdx.x;
    int d0 = blk * DPB;
    int t = threadIdx.x;
    int lane = t & 63, wave = t >> 6;
    int wm = wave & 1, wn = wave >> 1;
    int l15 = lane & 15, l4 = lane >> 4;

    for (int s = 0; s < 32; ++s) {
        int cid = t + s * 256;
        int c = cid >> 7;
        int ch = cid & 127;
        int g = c >> 4, dl = c & 15;
        u16x8 v = *(const u16x8*)(w_hh_bf + (size_t)(g * HID + d0 + dl) * HID + ch * 8);
        int chs = ch ^ (c & 7);
        *(u16x8*)(&Bs[c][chs * 8]) = v;
    }
    for (int s = t; s < 512; s += 256) {
        int b = s >> 4, dl = s & 15;
        c_sl[b][dl] = c0[b * HID + d0 + dl];
    }
    __syncthreads();

    int cA = wn * 32 + l15;
    int cB = cA + 16;
    int sw = cA & 7;
    int gA = cA >> 4, dA = cA & 15;
    int gB = cB >> 4, dB = cB & 15;

    int bb = t >> 3;
    int pr = t & 7;
    int dl0 = pr * 2;

    const float* gxTb = gxT + (size_t)blk * ((size_t)L_SEQ * 2048) + wm * 16 + l4 * 4;

    // prologue: prefetch gate biases for step 0
    f32x4 gxa0 = *(const f32x4*)(gxTb + (size_t)0 * 2048 + gA * 512 + dA * 32);
    f32x4 gxa1 = *(const f32x4*)(gxTb + (size_t)0 * 2048 + gB * 512 + dB * 32);

    for (int i = 0; i < L_SEQ; ++i) {
        const u16* hb = hb_hist + (size_t)i * (BSZ * HID);
        const u16* aptr = hb + (size_t)(wm * 16 + l15) * HID + l4 * 8;

        // issue all 32 A-fragment loads (bypass caches)
        u16x8 afr[32];
#pragma unroll
        for (int kk = 0; kk < 32; ++kk)
            asm volatile("global_load_dwordx4 %0, %1, off offset:%c2 sc0 sc1"
                         : "=v"(afr[kk])
                         : "v"(aptr), "n"(kk * 64));

        // consume-as-arrive poll: MFMA each chunk as soon as its ballot clears
        f32x4 acc0 = {0.f, 0.f, 0.f, 0.f}, acc1 = {0.f, 0.f, 0.f, 0.f};
        unsigned pend = 0xFFFFFFFFu;
        for (;;) {
            asm volatile("s_waitcnt vmcnt(0)" ::: "memory");
            __builtin_amdgcn_sched_barrier(0);
            unsigned done = 0;
#pragma unroll
            for (int kk = 0; kk < 32; ++kk) {
                if (pend & (1u << kk)) {
                    if (__ballot(umax4(afr[kk]) == SENT) == 0) {
                        bf16x8 af = __builtin_bit_cast(bf16x8, afr[kk]);
                        int ch = kk * 4 + l4;
                        bf16x8 b0 = __builtin_bit_cast(bf16x8, *(const u16x8*)(&Bs[cA][(ch ^ sw) * 8]));
                        bf16x8 b1 = __builtin_bit_cast(bf16x8, *(const u16x8*)(&Bs[cB][(ch ^ sw) * 8]));
                        acc0 = __builtin_amdgcn_mfma_f32_16x16x32_bf16(af, b0, acc0, 0, 0, 0);
                        acc1 = __builtin_amdgcn_mfma_f32_16x16x32_bf16(af, b1, acc1, 0, 0, 0);
                        done |= 1u << kk;
                    }
                }
            }
            pend &= ~done;
            if (!pend) break;
#pragma unroll
            for (int kk = 0; kk < 32; ++kk)
                if (pend & (1u << kk))
                    asm volatile("global_load_dwordx4 %0, %1, off offset:%c2 sc0 sc1"
                                 : "=v"(afr[kk])
                                 : "v"(aptr), "n"(kk * 64));
            __builtin_amdgcn_s_sleep(1);
        }
        __builtin_amdgcn_sched_barrier(0);

#pragma unroll
        for (int r = 0; r < 4; ++r) {
            int m = wm * 16 + l4 * 4 + r;
            gsm[gA][m][dA] = acc0[r] + gxa0[r];
            gsm[gB][m][dB] = acc1[r] + gxa1[r];
        }
        __syncthreads();

        // cell update: thread handles (bb, dl0) and (bb, dl0+1); publish h ASAP
        u16* hb_next = hb_hist + (size_t)(i + 1) * (BSZ * HID);
        float hn01[2];
#pragma unroll
        for (int q = 0; q < 2; ++q) {
            int dl = dl0 + q;
            float ig = gsm[0][bb][dl], fg = gsm[1][bb][dl];
            float gg = gsm[2][bb][dl], og = gsm[3][bb][dl];
            float cn = fast_sigm(fg) * c_sl[bb][dl] + fast_sigm(ig) * fast_tanh(gg);
            float hn = fast_sigm(og) * fast_tanh(cn);
            c_sl[bb][dl] = cn;
            hn01[q] = hn;
        }
        unsigned pk = (unsigned)f2bf(hn01[0]) | ((unsigned)f2bf(hn01[1]) << 16);
        __hip_atomic_store((unsigned*)(hb_next + bb * HID + d0 + dl0), pk,
                           __ATOMIC_RELAXED, __HIP_MEMORY_SCOPE_AGENT);
        if (i == L_SEQ - 1) {
            f32x2 hv = {hn01[0], hn01[1]};
            *(f32x2*)(out_tail + (size_t)bb * HID + d0 + dl0) = hv;
        }
        float pa = hn01[0] * Wv[d0 + dl0] + hn01[1] * Wv[d0 + dl0 + 1];
        float pb = hn01[0] * Uv[d0 + dl0] + hn01[1] * Uv[d0 + dl0 + 1];
        pa += __shfl_xor(pa, 1); pb += __shfl_xor(pb, 1);
        pa += __shfl_xor(pa, 2); pb += __shfl_xor(pb, 2);
        pa += __shfl_xor(pa, 4); pb += __shfl_xor(pb, 4);
        if (pr == 0) {
            f32x2 pv = {pa, pb};
            *(f32x2*)(part_ab + (((size_t)i * NB + blk) * BSZ + bb) * 2) = pv;
        }

        // prefetch gate biases for the NEXT step (completes during next poll)
        int inx = (i + 1 < L_SEQ) ? i + 1 : i;
        gxa0 = *(const f32x4*)(gxTb + (size_t)inx * 2048 + gA * 512 + dA * 32);
        gxa1 = *(const f32x4*)(gxTb + (size_t)inx * 2048 + gB * 512 + dB * 32);
    }

    for (int s = t; s < 512; s += 256) {
        int b2 = s >> 4, dl = s & 15;
        out_tail[(size_t)BSZ * HID + b2 * HID + d0 + dl] = c_sl[b2][dl];
    }
}

// ---------------- reduce a/b partials: a[i][b] = sum_blk part ----------------
__global__ __launch_bounds__(256) void reduce_ab_kernel(const float* __restrict__ part_ab,
                                                        float* __restrict__ a_arr,
                                                        float* __restrict__ b_arr) {
    int i = blockIdx.x;
    int t = threadIdx.x;
    int b = t & 31, q = t >> 5;
    float sa = 0.f, sb = 0.f;
    for (int j = 0; j < 8; ++j) {
        int blk = q * 8 + j;
        f32x2 v = *(const f32x2*)(part_ab + (((size_t)i * NB + blk) * BSZ + b) * 2);
        sa += v.x;
        sb += v.y;
    }
    __shared__ float ra[8][32], rb[8][32];
    ra[q][b] = sa;
    rb[q][b] = sb;
    __syncthreads();
    if (q == 0) {
        for (int j = 1; j < 8; ++j) { sa += ra[j][b]; sb += rb[j][b]; }
        a_arr[i * BSZ + b] = sa;
        b_arr[i * BSZ + b] = sb;
    }
}

// ---------------- attention: 8 queries per block, one batch per block.y (bf16 hist) ----------------
__global__ __launch_bounds__(256) void attn_kernel(const float* __restrict__ a_arr,
                                                   const float* __restrict__ b_arr,
                                                   const u16* __restrict__ hb_hist,
                                                   u16* __restrict__ ctx_bf) {
    int b = blockIdx.y;
    int i0 = blockIdx.x * 8;
    int t = threadIdx.x;
    __shared__ float att[8][256];
    __shared__ float red[256];

    float bt = b_arr[t * BSZ + b];
    for (int q = 0; q < 8; ++q) {
        int iq = i0 + q;
        att[q][t] = (t <= iq) ? tanhf(a_arr[iq * BSZ + b] + bt) : -INFINITY;
    }
    __syncthreads();
    for (int q = 0; q < 8; ++q) {
        int iq = i0 + q;
        red[t] = att[q][t];
        __syncthreads();
        for (int s = 128; s > 0; s >>= 1) {
            if (t < s) red[t] = fmaxf(red[t], red[t + s]);
            __syncthreads();
        }
        float m = red[0];
        __syncthreads();
        float e = (t <= iq) ? expf(att[q][t] - m) : 0.f;
        red[t] = e;
        __syncthreads();
        for (int s = 128; s > 0; s >>= 1) {
            if (t < s) red[t] += red[t + s];
            __syncthreads();
        }
        float sum = red[0];
        __syncthreads();
        att[q][t] = e / sum;
        __syncthreads();
    }

    int hc = t * 4;
    f32x4 accq[8];
    f32x4 zv = {0.f, 0.f, 0.f, 0.f};
    for (int q = 0; q < 8; ++q) accq[q] = zv;
    int imax = i0 + 7;
    for (int t2 = 0; t2 <= imax; ++t2) {
        u16x4 hq = *(const u16x4*)(hb_hist + (size_t)(t2 + 1) * (BSZ * HID) + (size_t)b * HID + hc);
        f32x4 hv = {BF2F(hq.x), BF2F(hq.y), BF2F(hq.z), BF2F(hq.w)};
        for (int q = 0; q < 8; ++q) accq[q] += hv * att[q][t2];
    }
    for (int q = 0; q < 8; ++q) {
        size_t row = (size_t)(i0 + q) * BSZ + b;
        u16x4 o = {f2bf(accq[q].x), f2bf(accq[q].y), f2bf(accq[q].z), f2bf(accq[q].w)};
        *(u16x4*)(ctx_bf + row * HID + hc) = o;
    }
}

// ---------------- in-place log_softmax over rows of [8192][10000], register-cached ----------------
__global__ __launch_bounds__(256) void logsoftmax_kernel(float* __restrict__ x, int V) {
    int row = blockIdx.x;
    float* p = x + (size_t)row * V;
    __shared__ float red[256];
    int t = threadIdx.x;
    float frag[40];
    float m = -INFINITY;
#pragma unroll
    for (int k = 0; k < 40; ++k) {
        int j = t + k * 256;
        if (j < VOC) {
            frag[k] = p[j];
            m = fmaxf(m, frag[k]);
        }
    }
    red[t] = m;
    __syncthreads();
    for (int s = 128; s > 0; s >>= 1) {
        if (t < s) red[t] = fmaxf(red[t], red[t + s]);
        __syncthreads();
    }
    m = red[0];
    __syncthreads();
    float sum = 0.f;
#pragma unroll
    for (int k = 0; k < 40; ++k) {
        int j = t + k * 256;
        if (j < VOC) sum += __expf(frag[k] - m);
    }
    red[t] = sum;
    __syncthreads();
    for (int s = 128; s > 0; s >>= 1) {
        if (t < s) red[t] += red[t + s];
        __syncthreads();
    }
    float lse = m + logf(red[0]);
#pragma unroll
    for (int k = 0; k < 40; ++k) {
        int j = t + k * 256;
        if (j < VOC) p[j] = frag[k] - lse;
    }
}

extern "C" void kernel_launch(void* const* d_in, const int* in_sizes, int n_in,
                              void* d_out, int out_size, void* d_ws, size_t ws_size,
                              hipStream_t stream) {
    const int* ids = (const int*)d_in[0];
    const float* h0 = (const float*)d_in[1];
    const float* c0 = (const float*)d_in[2];
    const float* emb_w = (const float*)d_in[3];
    const float* w_ih = (const float*)d_in[4];
    const float* w_hh = (const float*)d_in[5];
    const float* dec_w = (const float*)d_in[6];
    const float* dec_b = (const float*)d_in[7];
    const float* Wv = (const float*)d_in[8];
    const float* Uv = (const float*)d_in[9];

    char* p = (char*)d_ws;
    auto alloc = [&](size_t bytes) {
        void* r = (void*)p;
        p += (bytes + 255) & ~(size_t)255;
        return r;
    };
    u16* w_ih_bf = (u16*)alloc((size_t)G4 * NIN * 2);                 // 8 MiB
    u16* w_hh_bf = (u16*)alloc((size_t)G4 * HID * 2);                 // 8 MiB
    u16* dec_w_bf = (u16*)alloc((size_t)VOC * HID * 2);               // 20 MiB
    char* hbreg = (char*)alloc((size_t)(L_SEQ + 1) * BSZ * HID * 2);  // 16.84 MiB: A_emb -> hb_hist
    u16* ctx_bf = (u16*)alloc((size_t)MROWS * HID * 2);               // 16 MiB
    float* part_ab = (float*)alloc((size_t)L_SEQ * NB * BSZ * 2 * 4); // 4 MiB
    float* a_arr = (float*)alloc((size_t)L_SEQ * BSZ * 4);
    float* b_arr = (float*)alloc((size_t)L_SEQ * BSZ * 4);

    u16* A_emb = (u16*)hbreg;    // phase-1 only
    u16* hb_hist = (u16*)hbreg;  // recurrence
    float* out = (float*)d_out;
    float* gxT = out;  // transposed gx [64][256][4][16][32] f32 in d_out until logits overwrite
    float* out_tail = out + (size_t)MROWS * VOC;

    // phase 1: conversions + gx GEMM
    cvt_bf16_kernel<<<G4 * NIN / 1024, 256, 0, stream>>>(w_ih, w_ih_bf, G4 * NIN / 4);
    cvt_bf16_kernel<<<G4 * HID / 1024, 256, 0, stream>>>(w_hh, w_hh_bf, G4 * HID / 4);
    cvt_bf16_kernel<<<(VOC * HID / 4 + 255) / 256, 256, 0, stream>>>(dec_w, dec_w_bf, VOC * HID / 4);
    gather_emb_kernel<<<MROWS, 256, 0, stream>>>(ids, emb_w, A_emb);
    gemm_gxT_kernel<<<dim3(MROWS / 128, G4 / 128), 256, 0, stream>>>(A_emb, w_ih_bf, gxT);

    // phase 2: sentinel-fill slots 1..256, h(0) into slot 0 (A_emb dead now)
    hipMemsetAsync(hb_hist + (size_t)BSZ * HID, 0xFF, (size_t)L_SEQ * BSZ * HID * 2, stream);
    cvt_bf16_kernel<<<BSZ * HID / 1024, 256, 0, stream>>>(h0, hb_hist, BSZ * HID / 4);

    // phase 3: persistent recurrence (cooperative, 64 blocks)
    {
        const float* c0a = c0;
        const u16* whha = w_hh_bf;
        const float* gxa = gxT;
        const float* Wa = Wv;
        const float* Ua = Uv;
        u16* hba = hb_hist;
        float* tail = out_tail;
        float* pab = part_ab;
        void* args[] = {&c0a, &whha, &gxa, &Wa, &Ua, &hba, &tail, &pab};
        hipLaunchCooperativeKernel((const void*)lstm_seq_kernel, dim3(NB), dim3(256), args, 0,
                                   stream);
    }
    // phase 4: tail pipeline
    reduce_ab_kernel<<<L_SEQ, 256, 0, stream>>>(part_ab, a_arr, b_arr);
    attn_kernel<<<dim3(L_SEQ / 8, BSZ), 256, 0, stream>>>(a_arr, b_arr, hb_hist, ctx_bf);
    gemm_bt_kernel<<<dim3(MROWS / 128, (VOC + 127) / 128), 256, 0, stream>>>(ctx_bf, dec_w_bf, out,
                                                                             dec_b, MROWS, VOC, HID);
    logsoftmax_kernel<<<MROWS, 256, 0, stream>>>(out, VOC);
}

// Round 12
// 2517.484 us; speedup vs baseline: 1.0349x; 1.0349x over previous
//
#include <hip/hip_runtime.h>
#include <math.h>

typedef unsigned short u16;
typedef unsigned u32;
typedef unsigned long long u64;
typedef float f32x4 __attribute__((ext_vector_type(4)));
typedef float f32x2 __attribute__((ext_vector_type(2)));
typedef __bf16 bf16x8 __attribute__((ext_vector_type(8)));
typedef u16 u16x8 __attribute__((ext_vector_type(8)));
typedef u16 u16x4 __attribute__((ext_vector_type(4)));
typedef u32 u32x4 __attribute__((ext_vector_type(4)));
typedef u32 u32x2 __attribute__((ext_vector_type(2)));

#define L_SEQ 256
#define BSZ 32
#define HID 1024
#define NIN 1024
#define VOC 10000
#define G4 4096
#define MROWS 8192
#define NB 64    // recurrence blocks
#define NW 160   // gemm1 worker blocks
#define DPB 16   // h-dims per block
#define SENT 0xFFFFFFFFu

__device__ __forceinline__ u16 f2bf(float f) {
    unsigned u = __float_as_uint(f);
    unsigned r = u + 0x7FFFu + ((u >> 16) & 1u);
    return (u16)(r >> 16);
}
#define BF2F(x) __builtin_bit_cast(float, (u32)((u16)(x)) << 16)

__device__ __forceinline__ float fast_sigm(float x) {
    x = fminf(fmaxf(x, -15.f), 15.f);
    return __builtin_amdgcn_rcpf(1.f + __expf(-x));
}
__device__ __forceinline__ float fast_tanh(float x) {
    x = fminf(fmaxf(x, -15.f), 15.f);
    float t = __expf(2.f * x);
    return (t - 1.f) * __builtin_amdgcn_rcpf(t + 1.f);
}
__device__ __forceinline__ unsigned umax4(u16x8 v) {
    u32x4 c = __builtin_bit_cast(u32x4, v);
    unsigned a = c.x > c.y ? c.x : c.y;
    unsigned b = c.z > c.w ? c.z : c.w;
    return a > b ? a : b;
}

// ---------------- converters ----------------
__global__ __launch_bounds__(256) void cvt_bf16_kernel(const float* __restrict__ in,
                                                       u16* __restrict__ out, int n4) {
    int idx = blockIdx.x * 256 + threadIdx.x;
    if (idx < n4) {
        f32x4 v = *(const f32x4*)(in + (size_t)idx * 4);
        u16x4 o = {f2bf(v.x), f2bf(v.y), f2bf(v.z), f2bf(v.w)};
        *(u16x4*)(out + (size_t)idx * 4) = o;
    }
}

__global__ __launch_bounds__(256) void gather_emb_kernel(const int* __restrict__ ids,
                                                         const float* __restrict__ emb_w,
                                                         u16* __restrict__ out) {
    int m = blockIdx.x;
    int id = ids[m];
    const float* src = emb_w + (size_t)id * NIN;
    u16* dst = out + (size_t)m * NIN;
    int t = threadIdx.x;
    f32x4 v = *(const f32x4*)(src + t * 4);
    u16x4 o = {f2bf(v.x), f2bf(v.y), f2bf(v.z), f2bf(v.w)};
    *(u16x4*)(dst + t * 4) = o;
}

// ---------------- decoder GEMM: C[M][N] = A[M][K] * B[N][K]^T + bias ----------------
__global__ __launch_bounds__(256) void gemm_bt_kernel(const u16* __restrict__ A,
                                                      const u16* __restrict__ B,
                                                      float* __restrict__ C,
                                                      const float* __restrict__ bias,
                                                      int M, int N, int K) {
    int m0 = blockIdx.x * 128;
    int n0 = blockIdx.y * 128;
    __shared__ alignas(16) u16 As[128][40];
    __shared__ alignas(16) u16 Bs[128][40];
    int t = threadIdx.x;
    int lane = t & 63, wave = t >> 6;
    int wr = wave >> 1, wc = wave & 1;
    int l15 = lane & 15, l4 = lane >> 4;

    f32x4 acc[4][4];
    f32x4 zv = {0.f, 0.f, 0.f, 0.f};
    for (int mi = 0; mi < 4; ++mi)
        for (int ni = 0; ni < 4; ++ni) acc[mi][ni] = zv;

    for (int k0 = 0; k0 < K; k0 += 32) {
        for (int s = 0; s < 2; ++s) {
            int task = t + s * 256;
            int row = task >> 2, kof = (task & 3) * 8;
            u16x8 av = *(const u16x8*)(A + (size_t)(m0 + row) * K + k0 + kof);
            *(u16x8*)(&As[row][kof]) = av;
            int brow = n0 + row;
            u16x8 bv = {0, 0, 0, 0, 0, 0, 0, 0};
            if (brow < N) bv = *(const u16x8*)(B + (size_t)brow * K + k0 + kof);
            *(u16x8*)(&Bs[row][kof]) = bv;
        }
        __syncthreads();
        bf16x8 af[4], bfr[4];
        for (int mi = 0; mi < 4; ++mi)
            af[mi] = __builtin_bit_cast(bf16x8, *(const u16x8*)(&As[wr * 64 + mi * 16 + l15][l4 * 8]));
        for (int ni = 0; ni < 4; ++ni)
            bfr[ni] = __builtin_bit_cast(bf16x8, *(const u16x8*)(&Bs[wc * 64 + ni * 16 + l15][l4 * 8]));
        for (int mi = 0; mi < 4; ++mi)
            for (int ni = 0; ni < 4; ++ni)
                acc[mi][ni] = __builtin_amdgcn_mfma_f32_16x16x32_bf16(af[mi], bfr[ni], acc[mi][ni], 0, 0, 0);
        __syncthreads();
    }

    for (int mi = 0; mi < 4; ++mi)
        for (int ni = 0; ni < 4; ++ni) {
            int col = n0 + wc * 64 + ni * 16 + l15;
            if (col < N) {
                float bb = bias ? bias[col] : 0.f;
                int rbase = m0 + wr * 64 + mi * 16 + l4 * 4;
                for (int r = 0; r < 4; ++r)
                    C[(size_t)(rbase + r) * N + col] = acc[mi][ni][r] + bb;
            }
        }
}

// ---------------- fused recurrence + gemm1 workers (PLAIN launch, 224 blocks = 1/CU) ----------------
// No grid barrier anywhere -> plain launch is safe. LDS ~139KB forces 1 block/CU; grid 224 <= 256 CUs
// so all blocks are dispatched immediately (de-facto co-resident; workers are pure producers anyway).
// bid 0..63:   r9-exact recurrence; gxT gate biases consumed via sentinel data-poll (bf16).
// bid 64..223: gemm1 producers: gxT tile = emb_tile @ w_ih_tile^T, published write-through.
__global__ __launch_bounds__(256, 1) void lstm_seq_kernel(
    const float* __restrict__ c0, const u16* __restrict__ w_hh_bf, u16* __restrict__ gxT,
    const float* __restrict__ Wv, const float* __restrict__ Uv, u16* __restrict__ hb_hist,
    float* __restrict__ out_tail, float* __restrict__ part_ab, const u16* __restrict__ A_emb,
    const u16* __restrict__ w_ih_bf) {
    __shared__ alignas(16) u16 Bs[64][1024];  // recurrence: w_hh slice; workers: As2/Bs2 tiles
    __shared__ float gsm[4][32][17];
    __shared__ float c_sl[32][17];

    int blk = blockIdx.x;
    int t = threadIdx.x;
    int lane = t & 63, wave = t >> 6;
    int l15 = lane & 15, l4 = lane >> 4;

    if (blk >= NB) {
        // =========== ROLE 2: gemm1 worker ===========
        u16(*As2)[40] = (u16(*)[40])(&Bs[0][0]);
        u16(*Bs2)[40] = (u16(*)[40])((char*)(&Bs[0][0]) + 10240);
        int wr = wave >> 1, wc = wave & 1;
        for (int tau = blk - NB; tau < 2048; tau += NW) {
            int m0 = (tau >> 5) * 128;  // i-major: low i-tiles first across all workers
            int n0 = (tau & 31) * 128;
            f32x4 acc[4][4];
            f32x4 zv = {0.f, 0.f, 0.f, 0.f};
            for (int mi = 0; mi < 4; ++mi)
                for (int ni = 0; ni < 4; ++ni) acc[mi][ni] = zv;
            for (int k0 = 0; k0 < NIN; k0 += 32) {
                for (int s = 0; s < 2; ++s) {
                    int task = t + s * 256;
                    int row = task >> 2, kof = (task & 3) * 8;
                    *(u16x8*)(&As2[row][kof]) =
                        *(const u16x8*)(A_emb + (size_t)(m0 + row) * NIN + k0 + kof);
                    *(u16x8*)(&Bs2[row][kof]) =
                        *(const u16x8*)(w_ih_bf + (size_t)(n0 + row) * NIN + k0 + kof);
                }
                __syncthreads();
                bf16x8 af[4], bfr[4];
                for (int mi = 0; mi < 4; ++mi)
                    af[mi] = __builtin_bit_cast(bf16x8,
                                                *(const u16x8*)(&As2[wr * 64 + mi * 16 + l15][l4 * 8]));
                for (int ni = 0; ni < 4; ++ni)
                    bfr[ni] = __builtin_bit_cast(bf16x8,
                                                 *(const u16x8*)(&Bs2[wc * 64 + ni * 16 + l15][l4 * 8]));
                for (int mi = 0; mi < 4; ++mi)
                    for (int ni = 0; ni < 4; ++ni)
                        acc[mi][ni] =
                            __builtin_amdgcn_mfma_f32_16x16x32_bf16(af[mi], bfr[ni], acc[mi][ni], 0, 0, 0);
                __syncthreads();
            }
            // epilogue: transposed bf16 publish (write-through u64 atomics)
            for (int mi = 0; mi < 4; ++mi)
                for (int ni = 0; ni < 4; ++ni) {
                    int n = n0 + wc * 64 + ni * 16 + l15;
                    int g = n >> 10, dd = n & 1023;
                    int dblk = dd >> 4, dl = dd & 15;
                    int mbase = m0 + wr * 64 + mi * 16 + l4 * 4;
                    int i = mbase >> 5, bb2 = mbase & 31;
                    size_t idx = ((((size_t)dblk * L_SEQ + i) * 4 + g) * 16 + dl) * 32 + bb2;
                    u32 lo = (u32)f2bf(acc[mi][ni][0]) | ((u32)f2bf(acc[mi][ni][1]) << 16);
                    u32 hi = (u32)f2bf(acc[mi][ni][2]) | ((u32)f2bf(acc[mi][ni][3]) << 16);
                    u64 pk = (u64)lo | ((u64)hi << 32);
                    __hip_atomic_store((u64*)(gxT + idx), pk, __ATOMIC_RELAXED,
                                       __HIP_MEMORY_SCOPE_AGENT);
                }
        }
        return;
    }

    // =========== ROLE 1: recurrence (r9-exact + gxT sentinel poll) ===========
    int d0 = blk * DPB;
    int wm = wave & 1, wn = wave >> 1;

    for (int s = 0; s < 32; ++s) {
        int cid = t + s * 256;
        int c = cid >> 7;
        int ch = cid & 127;
        int g = c >> 4, dl = c & 15;
        u16x8 v = *(const u16x8*)(w_hh_bf + (size_t)(g * HID + d0 + dl) * HID + ch * 8);
        int chs = ch ^ (c & 7);
        *(u16x8*)(&Bs[c][chs * 8]) = v;
    }
    for (int s = t; s < 512; s += 256) {
        int b = s >> 4, dl = s & 15;
        c_sl[b][dl] = c0[b * HID + d0 + dl];
    }
    __syncthreads();

    int cA = wn * 32 + l15;
    int cB = cA + 16;
    int sw = cA & 7;
    int gA = cA >> 4, dA = cA & 15;
    int gB = cB >> 4, dB = cB & 15;

    int bb = t >> 3;
    int pr = t & 7;
    int dl0 = pr * 2;

    const u16* gxTb = gxT + (size_t)blk * ((size_t)L_SEQ * 2048) + wm * 16 + l4 * 4;

    // prologue: issue gate-bias loads for step 0 (validated at use)
    u16x4 gw0, gw1;
    {
        const u16* p0 = gxTb + gA * 512 + dA * 32;
        const u16* p1 = gxTb + gB * 512 + dB * 32;
        asm volatile("global_load_dwordx2 %0, %1, off sc0 sc1" : "=v"(gw0) : "v"(p0));
        asm volatile("global_load_dwordx2 %0, %1, off sc0 sc1" : "=v"(gw1) : "v"(p1));
    }

    for (int i = 0; i < L_SEQ; ++i) {
        const u16* hb = hb_hist + (size_t)i * (BSZ * HID);
        const u16* aptr = hb + (size_t)(wm * 16 + l15) * HID + l4 * 8;
        const u16* cp0 = gxTb + (size_t)i * 2048 + gA * 512 + dA * 32;
        const u16* cp1 = gxTb + (size_t)i * 2048 + gB * 512 + dB * 32;

        // issue all 32 A-fragment loads (bypass caches)
        u16x8 afr[32];
#pragma unroll
        for (int kk = 0; kk < 32; ++kk)
            asm volatile("global_load_dwordx4 %0, %1, off offset:%c2 sc0 sc1"
                         : "=v"(afr[kk])
                         : "v"(aptr), "n"(kk * 64));

        // consume-as-arrive poll (also drains the gw prefetch)
        f32x4 acc0 = {0.f, 0.f, 0.f, 0.f}, acc1 = {0.f, 0.f, 0.f, 0.f};
        unsigned pend = 0xFFFFFFFFu;
        for (;;) {
            asm volatile("s_waitcnt vmcnt(0)" ::: "memory");
            __builtin_amdgcn_sched_barrier(0);
            unsigned done = 0;
#pragma unroll
            for (int kk = 0; kk < 32; ++kk) {
                if (pend & (1u << kk)) {
                    if (__ballot(umax4(afr[kk]) == SENT) == 0) {
                        bf16x8 af = __builtin_bit_cast(bf16x8, afr[kk]);
                        int ch = kk * 4 + l4;
                        bf16x8 b0 = __builtin_bit_cast(bf16x8, *(const u16x8*)(&Bs[cA][(ch ^ sw) * 8]));
                        bf16x8 b1 = __builtin_bit_cast(bf16x8, *(const u16x8*)(&Bs[cB][(ch ^ sw) * 8]));
                        acc0 = __builtin_amdgcn_mfma_f32_16x16x32_bf16(af, b0, acc0, 0, 0, 0);
                        acc1 = __builtin_amdgcn_mfma_f32_16x16x32_bf16(af, b1, acc1, 0, 0, 0);
                        done |= 1u << kk;
                    }
                }
            }
            pend &= ~done;
            if (!pend) break;
#pragma unroll
            for (int kk = 0; kk < 32; ++kk)
                if (pend & (1u << kk))
                    asm volatile("global_load_dwordx4 %0, %1, off offset:%c2 sc0 sc1"
                                 : "=v"(afr[kk])
                                 : "v"(aptr), "n"(kk * 64));
            __builtin_amdgcn_s_sleep(1);
        }
        __builtin_amdgcn_sched_barrier(0);

        // validate prefetched gate biases (sentinel poll; workers run far ahead)
        for (;;) {
            u32x2 w0 = __builtin_bit_cast(u32x2, gw0);
            u32x2 w1 = __builtin_bit_cast(u32x2, gw1);
            if (__ballot(w0.x == SENT || w0.y == SENT || w1.x == SENT || w1.y == SENT) == 0) break;
            __builtin_amdgcn_s_sleep(4);
            asm volatile("global_load_dwordx2 %0, %1, off sc0 sc1" : "=v"(gw0) : "v"(cp0));
            asm volatile("global_load_dwordx2 %0, %1, off sc0 sc1" : "=v"(gw1) : "v"(cp1));
            asm volatile("s_waitcnt vmcnt(0)" ::: "memory");
            __builtin_amdgcn_sched_barrier(0);
        }

#pragma unroll
        for (int r = 0; r < 4; ++r) {
            int m = wm * 16 + l4 * 4 + r;
            gsm[gA][m][dA] = acc0[r] + BF2F(gw0[r]);
            gsm[gB][m][dB] = acc1[r] + BF2F(gw1[r]);
        }
        __syncthreads();

        // cell update: thread handles (bb, dl0) and (bb, dl0+1); publish h ASAP
        u16* hb_next = hb_hist + (size_t)(i + 1) * (BSZ * HID);
        float hn01[2];
#pragma unroll
        for (int q = 0; q < 2; ++q) {
            int dl = dl0 + q;
            float ig = gsm[0][bb][dl], fg = gsm[1][bb][dl];
            float gg = gsm[2][bb][dl], og = gsm[3][bb][dl];
            float cn = fast_sigm(fg) * c_sl[bb][dl] + fast_sigm(ig) * fast_tanh(gg);
            float hn = fast_sigm(og) * fast_tanh(cn);
            c_sl[bb][dl] = cn;
            hn01[q] = hn;
        }
        unsigned pk = (unsigned)f2bf(hn01[0]) | ((unsigned)f2bf(hn01[1]) << 16);
        __hip_atomic_store((unsigned*)(hb_next + bb * HID + d0 + dl0), pk,
                           __ATOMIC_RELAXED, __HIP_MEMORY_SCOPE_AGENT);
        if (i == L_SEQ - 1) {
            f32x2 hv = {hn01[0], hn01[1]};
            *(f32x2*)(out_tail + (size_t)bb * HID + d0 + dl0) = hv;
        }
        float pa = hn01[0] * Wv[d0 + dl0] + hn01[1] * Wv[d0 + dl0 + 1];
        float pb = hn01[0] * Uv[d0 + dl0] + hn01[1] * Uv[d0 + dl0 + 1];
        pa += __shfl_xor(pa, 1); pb += __shfl_xor(pb, 1);
        pa += __shfl_xor(pa, 2); pb += __shfl_xor(pb, 2);
        pa += __shfl_xor(pa, 4); pb += __shfl_xor(pb, 4);
        if (pr == 0) {
            f32x2 pv = {pa, pb};
            *(f32x2*)(part_ab + (((size_t)i * NB + blk) * BSZ + bb) * 2) = pv;
        }

        // prefetch gate biases for the NEXT step (land during next h-poll)
        {
            int inx = (i + 1 < L_SEQ) ? i + 1 : i;
            const u16* np0 = gxTb + (size_t)inx * 2048 + gA * 512 + dA * 32;
            const u16* np1 = gxTb + (size_t)inx * 2048 + gB * 512 + dB * 32;
            asm volatile("global_load_dwordx2 %0, %1, off sc0 sc1" : "=v"(gw0) : "v"(np0));
            asm volatile("global_load_dwordx2 %0, %1, off sc0 sc1" : "=v"(gw1) : "v"(np1));
        }
    }

    for (int s = t; s < 512; s += 256) {
        int b2 = s >> 4, dl = s & 15;
        out_tail[(size_t)BSZ * HID + b2 * HID + d0 + dl] = c_sl[b2][dl];
    }
}

// ---------------- reduce a/b partials: a[i][b] = sum_blk part ----------------
__global__ __launch_bounds__(256) void reduce_ab_kernel(const float* __restrict__ part_ab,
                                                        float* __restrict__ a_arr,
                                                        float* __restrict__ b_arr) {
    int i = blockIdx.x;
    int t = threadIdx.x;
    int b = t & 31, q = t >> 5;
    float sa = 0.f, sb = 0.f;
    for (int j = 0; j < 8; ++j) {
        int blk = q * 8 + j;
        f32x2 v = *(const f32x2*)(part_ab + (((size_t)i * NB + blk) * BSZ + b) * 2);
        sa += v.x;
        sb += v.y;
    }
    __shared__ float ra[8][32], rb[8][32];
    ra[q][b] = sa;
    rb[q][b] = sb;
    __syncthreads();
    if (q == 0) {
        for (int j = 1; j < 8; ++j) { sa += ra[j][b]; sb += rb[j][b]; }
        a_arr[i * BSZ + b] = sa;
        b_arr[i * BSZ + b] = sb;
    }
}

// ---------------- attention: 8 queries per block, one batch per block.y (bf16 hist) ----------------
__global__ __launch_bounds__(256) void attn_kernel(const float* __restrict__ a_arr,
                                                   const float* __restrict__ b_arr,
                                                   const u16* __restrict__ hb_hist,
                                                   u16* __restrict__ ctx_bf) {
    int b = blockIdx.y;
    int i0 = blockIdx.x * 8;
    int t = threadIdx.x;
    __shared__ float att[8][256];
    __shared__ float red[256];

    float bt = b_arr[t * BSZ + b];
    for (int q = 0; q < 8; ++q) {
        int iq = i0 + q;
        att[q][t] = (t <= iq) ? tanhf(a_arr[iq * BSZ + b] + bt) : -INFINITY;
    }
    __syncthreads();
    for (int q = 0; q < 8; ++q) {
        int iq = i0 + q;
        red[t] = att[q][t];
        __syncthreads();
        for (int s = 128; s > 0; s >>= 1) {
            if (t < s) red[t] = fmaxf(red[t], red[t + s]);
            __syncthreads();
        }
        float m = red[0];
        __syncthreads();
        float e = (t <= iq) ? expf(att[q][t] - m) : 0.f;
        red[t] = e;
        __syncthreads();
        for (int s = 128; s > 0; s >>= 1) {
            if (t < s) red[t] += red[t + s];
            __syncthreads();
        }
        float sum = red[0];
        __syncthreads();
        att[q][t] = e / sum;
        __syncthreads();
    }

    int hc = t * 4;
    f32x4 accq[8];
    f32x4 zv = {0.f, 0.f, 0.f, 0.f};
    for (int q = 0; q < 8; ++q) accq[q] = zv;
    int imax = i0 + 7;
    for (int t2 = 0; t2 <= imax; ++t2) {
        u16x4 hq = *(const u16x4*)(hb_hist + (size_t)(t2 + 1) * (BSZ * HID) + (size_t)b * HID + hc);
        f32x4 hv = {BF2F(hq.x), BF2F(hq.y), BF2F(hq.z), BF2F(hq.w)};
        for (int q = 0; q < 8; ++q) accq[q] += hv * att[q][t2];
    }
    for (int q = 0; q < 8; ++q) {
        size_t row = (size_t)(i0 + q) * BSZ + b;
        u16x4 o = {f2bf(accq[q].x), f2bf(accq[q].y), f2bf(accq[q].z), f2bf(accq[q].w)};
        *(u16x4*)(ctx_bf + row * HID + hc) = o;
    }
}

// ---------------- in-place log_softmax over rows of [8192][10000], register-cached ----------------
__global__ __launch_bounds__(256) void logsoftmax_kernel(float* __restrict__ x, int V) {
    int row = blockIdx.x;
    float* p = x + (size_t)row * V;
    __shared__ float red[256];
    int t = threadIdx.x;
    float frag[40];
    float m = -INFINITY;
#pragma unroll
    for (int k = 0; k < 40; ++k) {
        int j = t + k * 256;
        if (j < VOC) {
            frag[k] = p[j];
            m = fmaxf(m, frag[k]);
        }
    }
    red[t] = m;
    __syncthreads();
    for (int s = 128; s > 0; s >>= 1) {
        if (t < s) red[t] = fmaxf(red[t], red[t + s]);
        __syncthreads();
    }
    m = red[0];
    __syncthreads();
    float sum = 0.f;
#pragma unroll
    for (int k = 0; k < 40; ++k) {
        int j = t + k * 256;
        if (j < VOC) sum += __expf(frag[k] - m);
    }
    red[t] = sum;
    __syncthreads();
    for (int s = 128; s > 0; s >>= 1) {
        if (t < s) red[t] += red[t + s];
        __syncthreads();
    }
    float lse = m + logf(red[0]);
#pragma unroll
    for (int k = 0; k < 40; ++k) {
        int j = t + k * 256;
        if (j < VOC) p[j] = frag[k] - lse;
    }
}

extern "C" void kernel_launch(void* const* d_in, const int* in_sizes, int n_in,
                              void* d_out, int out_size, void* d_ws, size_t ws_size,
                              hipStream_t stream) {
    const int* ids = (const int*)d_in[0];
    const float* h0 = (const float*)d_in[1];
    const float* c0 = (const float*)d_in[2];
    const float* emb_w = (const float*)d_in[3];
    const float* w_ih = (const float*)d_in[4];
    const float* w_hh = (const float*)d_in[5];
    const float* dec_w = (const float*)d_in[6];
    const float* dec_b = (const float*)d_in[7];
    const float* Wv = (const float*)d_in[8];
    const float* Uv = (const float*)d_in[9];

    char* p = (char*)d_ws;
    auto alloc = [&](size_t bytes) {
        void* r = (void*)p;
        p += (bytes + 255) & ~(size_t)255;
        return r;
    };
    // ws total ~89 MiB
    u16* w_ih_bf = (u16*)alloc((size_t)G4 * NIN * 2);                 // 8 MiB
    u16* w_hh_bf = (u16*)alloc((size_t)G4 * HID * 2);                 // 8 MiB
    u16* dec_w_bf = (u16*)alloc((size_t)VOC * HID * 2);               // 20 MiB
    u16* hb_hist = (u16*)alloc((size_t)(L_SEQ + 1) * BSZ * HID * 2);  // 16.84 MiB (dedicated)
    u16* A_emb = (u16*)alloc((size_t)MROWS * NIN * 2);                // 16 MiB (dedicated)
    u16* ctx_bf = (u16*)alloc((size_t)MROWS * HID * 2);               // 16 MiB
    float* part_ab = (float*)alloc((size_t)L_SEQ * NB * BSZ * 2 * 4); // 4 MiB
    float* a_arr = (float*)alloc((size_t)L_SEQ * BSZ * 4);
    float* b_arr = (float*)alloc((size_t)L_SEQ * BSZ * 4);

    float* out = (float*)d_out;
    u16* gxT = (u16*)d_out;  // bf16 transposed gx: first 64 MiB of d_out (dead before logits)
    float* out_tail = out + (size_t)MROWS * VOC;

    // phase 1: conversions + gathers (pre-kernels; kernel-boundary coherence for worker inputs)
    cvt_bf16_kernel<<<G4 * NIN / 1024, 256, 0, stream>>>(w_ih, w_ih_bf, G4 * NIN / 4);
    cvt_bf16_kernel<<<G4 * HID / 1024, 256, 0, stream>>>(w_hh, w_hh_bf, G4 * HID / 4);
    cvt_bf16_kernel<<<(VOC * HID / 4 + 255) / 256, 256, 0, stream>>>(dec_w, dec_w_bf, VOC * HID / 4);
    gather_emb_kernel<<<MROWS, 256, 0, stream>>>(ids, emb_w, A_emb);

    // phase 2: sentinel fills — gxT (all), hb_hist slots 1..256; h(0) into slot 0
    hipMemsetAsync(gxT, 0xFF, (size_t)MROWS * G4 * 2, stream);
    hipMemsetAsync(hb_hist + (size_t)BSZ * HID, 0xFF, (size_t)L_SEQ * BSZ * HID * 2, stream);
    cvt_bf16_kernel<<<BSZ * HID / 1024, 256, 0, stream>>>(h0, hb_hist, BSZ * HID / 4);

    // phase 3: fused recurrence + gemm1 — PLAIN launch (no grid barrier in kernel)
    lstm_seq_kernel<<<dim3(NB + NW), dim3(256), 0, stream>>>(c0, w_hh_bf, gxT, Wv, Uv, hb_hist,
                                                             out_tail, part_ab, A_emb, w_ih_bf);

    // phase 4: tail pipeline
    reduce_ab_kernel<<<L_SEQ, 256, 0, stream>>>(part_ab, a_arr, b_arr);
    attn_kernel<<<dim3(L_SEQ / 8, BSZ), 256, 0, stream>>>(a_arr, b_arr, hb_hist, ctx_bf);
    gemm_bt_kernel<<<dim3(MROWS / 128, (VOC + 127) / 128), 256, 0, stream>>>(ctx_bf, dec_w_bf, out,
                                                                             dec_b, MROWS, VOC, HID);
    logsoftmax_kernel<<<MROWS, 256, 0, stream>>>(out, VOC);
}

// Round 13
// 2447.428 us; speedup vs baseline: 1.0646x; 1.0286x over previous
//
#include <hip/hip_runtime.h>
#include <math.h>

typedef unsigned short u16;
typedef unsigned u32;
typedef unsigned long long u64;
typedef float f32x4 __attribute__((ext_vector_type(4)));
typedef float f32x2 __attribute__((ext_vector_type(2)));
typedef __bf16 bf16x8 __attribute__((ext_vector_type(8)));
typedef u16 u16x8 __attribute__((ext_vector_type(8)));
typedef u16 u16x4 __attribute__((ext_vector_type(4)));
typedef u32 u32x4 __attribute__((ext_vector_type(4)));
typedef u32 u32x2 __attribute__((ext_vector_type(2)));

#define L_SEQ 256
#define BSZ 32
#define HID 1024
#define NIN 1024
#define VOC 10000
#define G4 4096
#define MROWS 8192
#define NB 64    // recurrence blocks
#define NW 160   // gemm1 worker blocks
#define DPB 16   // h-dims per block
#define SENT 0xFFFFFFFFu
#define NT_N 79  // ceil(VOC/128)

__device__ __forceinline__ u16 f2bf(float f) {
    unsigned u = __float_as_uint(f);
    unsigned r = u + 0x7FFFu + ((u >> 16) & 1u);
    return (u16)(r >> 16);
}
#define BF2F(x) __builtin_bit_cast(float, (u32)((u16)(x)) << 16)

__device__ __forceinline__ float fast_sigm(float x) {
    x = fminf(fmaxf(x, -15.f), 15.f);
    return __builtin_amdgcn_rcpf(1.f + __expf(-x));
}
__device__ __forceinline__ float fast_tanh(float x) {
    x = fminf(fmaxf(x, -15.f), 15.f);
    float t = __expf(2.f * x);
    return (t - 1.f) * __builtin_amdgcn_rcpf(t + 1.f);
}
__device__ __forceinline__ unsigned umax4(u16x8 v) {
    u32x4 c = __builtin_bit_cast(u32x4, v);
    unsigned a = c.x > c.y ? c.x : c.y;
    unsigned b = c.z > c.w ? c.z : c.w;
    return a > b ? a : b;
}

// async global->LDS, 16B per lane; LDS base must be wave-uniform
typedef __attribute__((address_space(1))) const unsigned GA;
typedef __attribute__((address_space(3))) unsigned LA;
__device__ __forceinline__ void gload_lds16(const void* g, void* l) {
    __builtin_amdgcn_global_load_lds((GA*)g, (LA*)l, 16, 0, 0);
}

// ---------------- converters ----------------
__global__ __launch_bounds__(256) void cvt_bf16_kernel(const float* __restrict__ in,
                                                       u16* __restrict__ out, int n4) {
    int idx = blockIdx.x * 256 + threadIdx.x;
    if (idx < n4) {
        f32x4 v = *(const f32x4*)(in + (size_t)idx * 4);
        u16x4 o = {f2bf(v.x), f2bf(v.y), f2bf(v.z), f2bf(v.w)};
        *(u16x4*)(out + (size_t)idx * 4) = o;
    }
}

__global__ __launch_bounds__(256) void gather_emb_kernel(const int* __restrict__ ids,
                                                         const float* __restrict__ emb_w,
                                                         u16* __restrict__ out) {
    int m = blockIdx.x;
    int id = ids[m];
    const float* src = emb_w + (size_t)id * NIN;
    u16* dst = out + (size_t)m * NIN;
    int t = threadIdx.x;
    f32x4 v = *(const f32x4*)(src + t * 4);
    u16x4 o = {f2bf(v.x), f2bf(v.y), f2bf(v.z), f2bf(v.w)};
    *(u16x4*)(dst + t * 4) = o;
}

// ---------------- decoder GEMM (m97 pattern): global_load_lds staging + XCD swizzle ----------------
// C[8192][10000] = ctx[8192][1024] @ dec_w[10000][1024]^T + bias
__global__ __launch_bounds__(256) void gemm_dec_kernel(const u16* __restrict__ A,
                                                       const u16* __restrict__ B,
                                                       float* __restrict__ C,
                                                       const float* __restrict__ bias) {
    __shared__ alignas(16) u16 Asl[128 * 32];  // linear: row stride 32 elem (64 B)
    __shared__ alignas(16) u16 Bsl[128 * 32];
    int bid = blockIdx.x;
    // bijective XCD swizzle (nwg = 5056, % 8 == 0); n-major so each XCD's B-slice fits L2
    int swz = (bid & 7) * ((NT_N * 64) >> 3) + (bid >> 3);
    int nt = swz >> 6;          // 0..78
    int mt = swz & 63;          // 0..63
    int m0 = mt * 128, n0 = nt * 128;

    int t = threadIdx.x;
    int lane = t & 63, w = t >> 6;
    int wr = w >> 1, wc = w & 1;
    int l15 = lane & 15, l4 = lane >> 4;
    int rsub = lane >> 2;       // 0..15
    int kof = (lane & 3) * 8;   // element offset within 32-wide K slice

    f32x4 acc[4][4];
    f32x4 zv = {0.f, 0.f, 0.f, 0.f};
    for (int mi = 0; mi < 4; ++mi)
        for (int ni = 0; ni < 4; ++ni) acc[mi][ni] = zv;

    for (int k0 = 0; k0 < HID; k0 += 32) {
#pragma unroll
        for (int s = 0; s < 2; ++s) {
            int row = s * 64 + w * 16 + rsub;
            const u16* gA = A + (size_t)(m0 + row) * HID + k0 + kof;
            gload_lds16(gA, Asl + (s * 64 + w * 16) * 32);  // LDS base wave-uniform
            int brow = n0 + row;
            if (brow > VOC - 1) brow = VOC - 1;  // clamp; outputs guarded at write
            const u16* gB = B + (size_t)brow * HID + k0 + kof;
            gload_lds16(gB, Bsl + (s * 64 + w * 16) * 32);
        }
        __syncthreads();  // compiler drains vmcnt(0) before barrier
        bf16x8 af[4], bfr[4];
        for (int mi = 0; mi < 4; ++mi)
            af[mi] = __builtin_bit_cast(bf16x8,
                                        *(const u16x8*)(Asl + (wr * 64 + mi * 16 + l15) * 32 + l4 * 8));
        for (int ni = 0; ni < 4; ++ni)
            bfr[ni] = __builtin_bit_cast(bf16x8,
                                         *(const u16x8*)(Bsl + (wc * 64 + ni * 16 + l15) * 32 + l4 * 8));
        for (int mi = 0; mi < 4; ++mi)
            for (int ni = 0; ni < 4; ++ni)
                acc[mi][ni] = __builtin_amdgcn_mfma_f32_16x16x32_bf16(af[mi], bfr[ni], acc[mi][ni], 0, 0, 0);
        __syncthreads();
    }

    for (int mi = 0; mi < 4; ++mi)
        for (int ni = 0; ni < 4; ++ni) {
            int col = n0 + wc * 64 + ni * 16 + l15;
            if (col < VOC) {
                float bb = bias[col];
                int rbase = m0 + wr * 64 + mi * 16 + l4 * 4;
                for (int r = 0; r < 4; ++r)
                    C[(size_t)(rbase + r) * VOC + col] = acc[mi][ni][r] + bb;
            }
        }
}

// ---------------- fused recurrence + gemm1 workers (PLAIN launch, 224 blocks = 1/CU) ----------------
__global__ __launch_bounds__(256, 1) void lstm_seq_kernel(
    const float* __restrict__ c0, const u16* __restrict__ w_hh_bf, u16* __restrict__ gxT,
    const float* __restrict__ Wv, const float* __restrict__ Uv, u16* __restrict__ hb_hist,
    float* __restrict__ out_tail, float* __restrict__ part_ab, const u16* __restrict__ A_emb,
    const u16* __restrict__ w_ih_bf) {
    __shared__ alignas(16) u16 Bs[64][1024];  // recurrence: w_hh slice; workers: As2/Bs2 tiles
    __shared__ float gsm[4][32][17];
    __shared__ float c_sl[32][17];

    int blk = blockIdx.x;
    int t = threadIdx.x;
    int lane = t & 63, wave = t >> 6;
    int l15 = lane & 15, l4 = lane >> 4;

    if (blk >= NB) {
        // =========== ROLE 2: gemm1 worker ===========
        u16(*As2)[40] = (u16(*)[40])(&Bs[0][0]);
        u16(*Bs2)[40] = (u16(*)[40])((char*)(&Bs[0][0]) + 10240);
        int wr = wave >> 1, wc = wave & 1;
        for (int tau = blk - NB; tau < 2048; tau += NW) {
            int m0 = (tau >> 5) * 128;  // i-major: low i-tiles first across all workers
            int n0 = (tau & 31) * 128;
            f32x4 acc[4][4];
            f32x4 zv = {0.f, 0.f, 0.f, 0.f};
            for (int mi = 0; mi < 4; ++mi)
                for (int ni = 0; ni < 4; ++ni) acc[mi][ni] = zv;
            for (int k0 = 0; k0 < NIN; k0 += 32) {
                for (int s = 0; s < 2; ++s) {
                    int task = t + s * 256;
                    int row = task >> 2, kof = (task & 3) * 8;
                    *(u16x8*)(&As2[row][kof]) =
                        *(const u16x8*)(A_emb + (size_t)(m0 + row) * NIN + k0 + kof);
                    *(u16x8*)(&Bs2[row][kof]) =
                        *(const u16x8*)(w_ih_bf + (size_t)(n0 + row) * NIN + k0 + kof);
                }
                __syncthreads();
                bf16x8 af[4], bfr[4];
                for (int mi = 0; mi < 4; ++mi)
                    af[mi] = __builtin_bit_cast(bf16x8,
                                                *(const u16x8*)(&As2[wr * 64 + mi * 16 + l15][l4 * 8]));
                for (int ni = 0; ni < 4; ++ni)
                    bfr[ni] = __builtin_bit_cast(bf16x8,
                                                 *(const u16x8*)(&Bs2[wc * 64 + ni * 16 + l15][l4 * 8]));
                for (int mi = 0; mi < 4; ++mi)
                    for (int ni = 0; ni < 4; ++ni)
                        acc[mi][ni] =
                            __builtin_amdgcn_mfma_f32_16x16x32_bf16(af[mi], bfr[ni], acc[mi][ni], 0, 0, 0);
                __syncthreads();
            }
            // epilogue: transposed bf16 publish (write-through u64 atomics)
            for (int mi = 0; mi < 4; ++mi)
                for (int ni = 0; ni < 4; ++ni) {
                    int n = n0 + wc * 64 + ni * 16 + l15;
                    int g = n >> 10, dd = n & 1023;
                    int dblk = dd >> 4, dl = dd & 15;
                    int mbase = m0 + wr * 64 + mi * 16 + l4 * 4;
                    int i = mbase >> 5, bb2 = mbase & 31;
                    size_t idx = ((((size_t)dblk * L_SEQ + i) * 4 + g) * 16 + dl) * 32 + bb2;
                    u32 lo = (u32)f2bf(acc[mi][ni][0]) | ((u32)f2bf(acc[mi][ni][1]) << 16);
                    u32 hi = (u32)f2bf(acc[mi][ni][2]) | ((u32)f2bf(acc[mi][ni][3]) << 16);
                    u64 pk = (u64)lo | ((u64)hi << 32);
                    __hip_atomic_store((u64*)(gxT + idx), pk, __ATOMIC_RELAXED,
                                       __HIP_MEMORY_SCOPE_AGENT);
                }
        }
        return;
    }

    // =========== ROLE 1: recurrence (r9-exact + gxT sentinel poll) ===========
    int d0 = blk * DPB;
    int wm = wave & 1, wn = wave >> 1;

    for (int s = 0; s < 32; ++s) {
        int cid = t + s * 256;
        int c = cid >> 7;
        int ch = cid & 127;
        int g = c >> 4, dl = c & 15;
        u16x8 v = *(const u16x8*)(w_hh_bf + (size_t)(g * HID + d0 + dl) * HID + ch * 8);
        int chs = ch ^ (c & 7);
        *(u16x8*)(&Bs[c][chs * 8]) = v;
    }
    for (int s = t; s < 512; s += 256) {
        int b = s >> 4, dl = s & 15;
        c_sl[b][dl] = c0[b * HID + d0 + dl];
    }
    __syncthreads();

    int cA = wn * 32 + l15;
    int cB = cA + 16;
    int sw = cA & 7;
    int gA = cA >> 4, dA = cA & 15;
    int gB = cB >> 4, dB = cB & 15;

    int bb = t >> 3;
    int pr = t & 7;
    int dl0 = pr * 2;

    const u16* gxTb = gxT + (size_t)blk * ((size_t)L_SEQ * 2048) + wm * 16 + l4 * 4;

    // prologue: issue gate-bias loads for step 0 (validated at use)
    u16x4 gw0, gw1;
    {
        const u16* p0 = gxTb + gA * 512 + dA * 32;
        const u16* p1 = gxTb + gB * 512 + dB * 32;
        asm volatile("global_load_dwordx2 %0, %1, off sc0 sc1" : "=v"(gw0) : "v"(p0));
        asm volatile("global_load_dwordx2 %0, %1, off sc0 sc1" : "=v"(gw1) : "v"(p1));
    }

    for (int i = 0; i < L_SEQ; ++i) {
        const u16* hb = hb_hist + (size_t)i * (BSZ * HID);
        const u16* aptr = hb + (size_t)(wm * 16 + l15) * HID + l4 * 8;
        const u16* cp0 = gxTb + (size_t)i * 2048 + gA * 512 + dA * 32;
        const u16* cp1 = gxTb + (size_t)i * 2048 + gB * 512 + dB * 32;

        // issue all 32 A-fragment loads (bypass caches)
        u16x8 afr[32];
#pragma unroll
        for (int kk = 0; kk < 32; ++kk)
            asm volatile("global_load_dwordx4 %0, %1, off offset:%c2 sc0 sc1"
                         : "=v"(afr[kk])
                         : "v"(aptr), "n"(kk * 64));

        // consume-as-arrive poll (also drains the gw prefetch)
        f32x4 acc0 = {0.f, 0.f, 0.f, 0.f}, acc1 = {0.f, 0.f, 0.f, 0.f};
        unsigned pend = 0xFFFFFFFFu;
        for (;;) {
            asm volatile("s_waitcnt vmcnt(0)" ::: "memory");
            __builtin_amdgcn_sched_barrier(0);
            unsigned done = 0;
#pragma unroll
            for (int kk = 0; kk < 32; ++kk) {
                if (pend & (1u << kk)) {
                    if (__ballot(umax4(afr[kk]) == SENT) == 0) {
                        bf16x8 af = __builtin_bit_cast(bf16x8, afr[kk]);
                        int ch = kk * 4 + l4;
                        bf16x8 b0 = __builtin_bit_cast(bf16x8, *(const u16x8*)(&Bs[cA][(ch ^ sw) * 8]));
                        bf16x8 b1 = __builtin_bit_cast(bf16x8, *(const u16x8*)(&Bs[cB][(ch ^ sw) * 8]));
                        acc0 = __builtin_amdgcn_mfma_f32_16x16x32_bf16(af, b0, acc0, 0, 0, 0);
                        acc1 = __builtin_amdgcn_mfma_f32_16x16x32_bf16(af, b1, acc1, 0, 0, 0);
                        done |= 1u << kk;
                    }
                }
            }
            pend &= ~done;
            if (!pend) break;
#pragma unroll
            for (int kk = 0; kk < 32; ++kk)
                if (pend & (1u << kk))
                    asm volatile("global_load_dwordx4 %0, %1, off offset:%c2 sc0 sc1"
                                 : "=v"(afr[kk])
                                 : "v"(aptr), "n"(kk * 64));
            __builtin_amdgcn_s_sleep(1);
        }
        __builtin_amdgcn_sched_barrier(0);

        // validate prefetched gate biases (sentinel poll; workers run far ahead)
        for (;;) {
            u32x2 w0 = __builtin_bit_cast(u32x2, gw0);
            u32x2 w1 = __builtin_bit_cast(u32x2, gw1);
            if (__ballot(w0.x == SENT || w0.y == SENT || w1.x == SENT || w1.y == SENT) == 0) break;
            __builtin_amdgcn_s_sleep(4);
            asm volatile("global_load_dwordx2 %0, %1, off sc0 sc1" : "=v"(gw0) : "v"(cp0));
            asm volatile("global_load_dwordx2 %0, %1, off sc0 sc1" : "=v"(gw1) : "v"(cp1));
            asm volatile("s_waitcnt vmcnt(0)" ::: "memory");
            __builtin_amdgcn_sched_barrier(0);
        }

#pragma unroll
        for (int r = 0; r < 4; ++r) {
            int m = wm * 16 + l4 * 4 + r;
            gsm[gA][m][dA] = acc0[r] + BF2F(gw0[r]);
            gsm[gB][m][dB] = acc1[r] + BF2F(gw1[r]);
        }
        __syncthreads();

        // cell update: thread handles (bb, dl0) and (bb, dl0+1); publish h ASAP
        u16* hb_next = hb_hist + (size_t)(i + 1) * (BSZ * HID);
        float hn01[2];
#pragma unroll
        for (int q = 0; q < 2; ++q) {
            int dl = dl0 + q;
            float ig = gsm[0][bb][dl], fg = gsm[1][bb][dl];
            float gg = gsm[2][bb][dl], og = gsm[3][bb][dl];
            float cn = fast_sigm(fg) * c_sl[bb][dl] + fast_sigm(ig) * fast_tanh(gg);
            float hn = fast_sigm(og) * fast_tanh(cn);
            c_sl[bb][dl] = cn;
            hn01[q] = hn;
        }
        unsigned pk = (unsigned)f2bf(hn01[0]) | ((unsigned)f2bf(hn01[1]) << 16);
        __hip_atomic_store((unsigned*)(hb_next + bb * HID + d0 + dl0), pk,
                           __ATOMIC_RELAXED, __HIP_MEMORY_SCOPE_AGENT);
        if (i == L_SEQ - 1) {
            f32x2 hv = {hn01[0], hn01[1]};
            *(f32x2*)(out_tail + (size_t)bb * HID + d0 + dl0) = hv;
        }
        float pa = hn01[0] * Wv[d0 + dl0] + hn01[1] * Wv[d0 + dl0 + 1];
        float pb = hn01[0] * Uv[d0 + dl0] + hn01[1] * Uv[d0 + dl0 + 1];
        pa += __shfl_xor(pa, 1); pb += __shfl_xor(pb, 1);
        pa += __shfl_xor(pa, 2); pb += __shfl_xor(pb, 2);
        pa += __shfl_xor(pa, 4); pb += __shfl_xor(pb, 4);
        if (pr == 0) {
            f32x2 pv = {pa, pb};
            *(f32x2*)(part_ab + (((size_t)i * NB + blk) * BSZ + bb) * 2) = pv;
        }

        // prefetch gate biases for the NEXT step (land during next h-poll)
        {
            int inx = (i + 1 < L_SEQ) ? i + 1 : i;
            const u16* np0 = gxTb + (size_t)inx * 2048 + gA * 512 + dA * 32;
            const u16* np1 = gxTb + (size_t)inx * 2048 + gB * 512 + dB * 32;
            asm volatile("global_load_dwordx2 %0, %1, off sc0 sc1" : "=v"(gw0) : "v"(np0));
            asm volatile("global_load_dwordx2 %0, %1, off sc0 sc1" : "=v"(gw1) : "v"(np1));
        }
    }

    for (int s = t; s < 512; s += 256) {
        int b2 = s >> 4, dl = s & 15;
        out_tail[(size_t)BSZ * HID + b2 * HID + d0 + dl] = c_sl[b2][dl];
    }
}

// ---------------- reduce a/b partials: a[i][b] = sum_blk part ----------------
__global__ __launch_bounds__(256) void reduce_ab_kernel(const float* __restrict__ part_ab,
                                                        float* __restrict__ a_arr,
                                                        float* __restrict__ b_arr) {
    int i = blockIdx.x;
    int t = threadIdx.x;
    int b = t & 31, q = t >> 5;
    float sa = 0.f, sb = 0.f;
    for (int j = 0; j < 8; ++j) {
        int blk = q * 8 + j;
        f32x2 v = *(const f32x2*)(part_ab + (((size_t)i * NB + blk) * BSZ + b) * 2);
        sa += v.x;
        sb += v.y;
    }
    __shared__ float ra[8][32], rb[8][32];
    ra[q][b] = sa;
    rb[q][b] = sb;
    __syncthreads();
    if (q == 0) {
        for (int j = 1; j < 8; ++j) { sa += ra[j][b]; sb += rb[j][b]; }
        a_arr[i * BSZ + b] = sa;
        b_arr[i * BSZ + b] = sb;
    }
}

// ---------------- attention: 8 queries per block, one batch per block.y (bf16 hist) ----------------
__global__ __launch_bounds__(256) void attn_kernel(const float* __restrict__ a_arr,
                                                   const float* __restrict__ b_arr,
                                                   const u16* __restrict__ hb_hist,
                                                   u16* __restrict__ ctx_bf) {
    int b = blockIdx.y;
    int i0 = blockIdx.x * 8;
    int t = threadIdx.x;
    __shared__ float att[8][256];
    __shared__ float red[256];

    float bt = b_arr[t * BSZ + b];
    for (int q = 0; q < 8; ++q) {
        int iq = i0 + q;
        att[q][t] = (t <= iq) ? tanhf(a_arr[iq * BSZ + b] + bt) : -INFINITY;
    }
    __syncthreads();
    for (int q = 0; q < 8; ++q) {
        int iq = i0 + q;
        red[t] = att[q][t];
        __syncthreads();
        for (int s = 128; s > 0; s >>= 1) {
            if (t < s) red[t] = fmaxf(red[t], red[t + s]);
            __syncthreads();
        }
        float m = red[0];
        __syncthreads();
        float e = (t <= iq) ? expf(att[q][t] - m) : 0.f;
        red[t] = e;
        __syncthreads();
        for (int s = 128; s > 0; s >>= 1) {
            if (t < s) red[t] += red[t + s];
            __syncthreads();
        }
        float sum = red[0];
        __syncthreads();
        att[q][t] = e / sum;
        __syncthreads();
    }

    int hc = t * 4;
    f32x4 accq[8];
    f32x4 zv = {0.f, 0.f, 0.f, 0.f};
    for (int q = 0; q < 8; ++q) accq[q] = zv;
    int imax = i0 + 7;
    for (int t2 = 0; t2 <= imax; ++t2) {
        u16x4 hq = *(const u16x4*)(hb_hist + (size_t)(t2 + 1) * (BSZ * HID) + (size_t)b * HID + hc);
        f32x4 hv = {BF2F(hq.x), BF2F(hq.y), BF2F(hq.z), BF2F(hq.w)};
        for (int q = 0; q < 8; ++q) accq[q] += hv * att[q][t2];
    }
    for (int q = 0; q < 8; ++q) {
        size_t row = (size_t)(i0 + q) * BSZ + b;
        u16x4 o = {f2bf(accq[q].x), f2bf(accq[q].y), f2bf(accq[q].z), f2bf(accq[q].w)};
        *(u16x4*)(ctx_bf + row * HID + hc) = o;
    }
}

// ---------------- in-place log_softmax over rows of [8192][10000], register-cached ----------------
__global__ __launch_bounds__(256) void logsoftmax_kernel(float* __restrict__ x, int V) {
    int row = blockIdx.x;
    float* p = x + (size_t)row * V;
    __shared__ float red[256];
    int t = threadIdx.x;
    float frag[40];
    float m = -INFINITY;
#pragma unroll
    for (int k = 0; k < 40; ++k) {
        int j = t + k * 256;
        if (j < VOC) {
            frag[k] = p[j];
            m = fmaxf(m, frag[k]);
        }
    }
    red[t] = m;
    __syncthreads();
    for (int s = 128; s > 0; s >>= 1) {
        if (t < s) red[t] = fmaxf(red[t], red[t + s]);
        __syncthreads();
    }
    m = red[0];
    __syncthreads();
    float sum = 0.f;
#pragma unroll
    for (int k = 0; k < 40; ++k) {
        int j = t + k * 256;
        if (j < VOC) sum += __expf(frag[k] - m);
    }
    red[t] = sum;
    __syncthreads();
    for (int s = 128; s > 0; s >>= 1) {
        if (t < s) red[t] += red[t + s];
        __syncthreads();
    }
    float lse = m + logf(red[0]);
#pragma unroll
    for (int k = 0; k < 40; ++k) {
        int j = t + k * 256;
        if (j < VOC) p[j] = frag[k] - lse;
    }
}

extern "C" void kernel_launch(void* const* d_in, const int* in_sizes, int n_in,
                              void* d_out, int out_size, void* d_ws, size_t ws_size,
                              hipStream_t stream) {
    const int* ids = (const int*)d_in[0];
    const float* h0 = (const float*)d_in[1];
    const float* c0 = (const float*)d_in[2];
    const float* emb_w = (const float*)d_in[3];
    const float* w_ih = (const float*)d_in[4];
    const float* w_hh = (const float*)d_in[5];
    const float* dec_w = (const float*)d_in[6];
    const float* dec_b = (const float*)d_in[7];
    const float* Wv = (const float*)d_in[8];
    const float* Uv = (const float*)d_in[9];

    char* p = (char*)d_ws;
    auto alloc = [&](size_t bytes) {
        void* r = (void*)p;
        p += (bytes + 255) & ~(size_t)255;
        return r;
    };
    // ws total ~89 MiB
    u16* w_ih_bf = (u16*)alloc((size_t)G4 * NIN * 2);                 // 8 MiB
    u16* w_hh_bf = (u16*)alloc((size_t)G4 * HID * 2);                 // 8 MiB
    u16* dec_w_bf = (u16*)alloc((size_t)VOC * HID * 2);               // 20 MiB
    u16* hb_hist = (u16*)alloc((size_t)(L_SEQ + 1) * BSZ * HID * 2);  // 16.84 MiB (dedicated)
    u16* A_emb = (u16*)alloc((size_t)MROWS * NIN * 2);                // 16 MiB (dedicated)
    u16* ctx_bf = (u16*)alloc((size_t)MROWS * HID * 2);               // 16 MiB
    float* part_ab = (float*)alloc((size_t)L_SEQ * NB * BSZ * 2 * 4); // 4 MiB
    float* a_arr = (float*)alloc((size_t)L_SEQ * BSZ * 4);
    float* b_arr = (float*)alloc((size_t)L_SEQ * BSZ * 4);

    float* out = (float*)d_out;
    u16* gxT = (u16*)d_out;  // bf16 transposed gx: first 64 MiB of d_out (dead before logits)
    float* out_tail = out + (size_t)MROWS * VOC;

    // phase 1: conversions + gathers (pre-kernels; kernel-boundary coherence for worker inputs)
    cvt_bf16_kernel<<<G4 * NIN / 1024, 256, 0, stream>>>(w_ih, w_ih_bf, G4 * NIN / 4);
    cvt_bf16_kernel<<<G4 * HID / 1024, 256, 0, stream>>>(w_hh, w_hh_bf, G4 * HID / 4);
    cvt_bf16_kernel<<<(VOC * HID / 4 + 255) / 256, 256, 0, stream>>>(dec_w, dec_w_bf, VOC * HID / 4);
    gather_emb_kernel<<<MROWS, 256, 0, stream>>>(ids, emb_w, A_emb);

    // phase 2: sentinel fills — gxT (all), hb_hist slots 1..256; h(0) into slot 0
    hipMemsetAsync(gxT, 0xFF, (size_t)MROWS * G4 * 2, stream);
    hipMemsetAsync(hb_hist + (size_t)BSZ * HID, 0xFF, (size_t)L_SEQ * BSZ * HID * 2, stream);
    cvt_bf16_kernel<<<BSZ * HID / 1024, 256, 0, stream>>>(h0, hb_hist, BSZ * HID / 4);

    // phase 3: fused recurrence + gemm1 — PLAIN launch (no grid barrier in kernel)
    lstm_seq_kernel<<<dim3(NB + NW), dim3(256), 0, stream>>>(c0, w_hh_bf, gxT, Wv, Uv, hb_hist,
                                                             out_tail, part_ab, A_emb, w_ih_bf);

    // phase 4: tail pipeline
    reduce_ab_kernel<<<L_SEQ, 256, 0, stream>>>(part_ab, a_arr, b_arr);
    attn_kernel<<<dim3(L_SEQ / 8, BSZ), 256, 0, stream>>>(a_arr, b_arr, hb_hist, ctx_bf);
    gemm_dec_kernel<<<dim3(64 * NT_N), 256, 0, stream>>>(ctx_bf, dec_w_bf, out, dec_b);
    logsoftmax_kernel<<<MROWS, 256, 0, stream>>>(out, VOC);
}

// Round 14
// 2439.611 us; speedup vs baseline: 1.0680x; 1.0032x over previous
//
#include <hip/hip_runtime.h>
#include <math.h>

typedef unsigned short u16;
typedef unsigned u32;
typedef unsigned long long u64;
typedef float f32x4 __attribute__((ext_vector_type(4)));
typedef float f32x2 __attribute__((ext_vector_type(2)));
typedef __bf16 bf16x8 __attribute__((ext_vector_type(8)));
typedef u16 u16x8 __attribute__((ext_vector_type(8)));
typedef u16 u16x4 __attribute__((ext_vector_type(4)));
typedef u32 u32x4 __attribute__((ext_vector_type(4)));
typedef u32 u32x2 __attribute__((ext_vector_type(2)));

#define L_SEQ 256
#define BSZ 32
#define HID 1024
#define NIN 1024
#define VOC 10000
#define G4 4096
#define MROWS 8192
#define NB 64    // recurrence blocks
#define NW 160   // gemm1 worker blocks
#define DPB 16   // h-dims per block
#define SENT 0xFFFFFFFFu
#define NT_N 79  // ceil(VOC/128)

#define NC1 (G4 * NIN / 4)
#define NC2 (G4 * HID / 4)
#define NC3 (VOC * HID / 4)

__device__ __forceinline__ u16 f2bf(float f) {
    unsigned u = __float_as_uint(f);
    unsigned r = u + 0x7FFFu + ((u >> 16) & 1u);
    return (u16)(r >> 16);
}
#define BF2F(x) __builtin_bit_cast(float, (u32)((u16)(x)) << 16)

__device__ __forceinline__ float fast_sigm(float x) {
    x = fminf(fmaxf(x, -15.f), 15.f);
    return __builtin_amdgcn_rcpf(1.f + __expf(-x));
}
__device__ __forceinline__ float fast_tanh(float x) {
    x = fminf(fmaxf(x, -15.f), 15.f);
    float t = __expf(2.f * x);
    return (t - 1.f) * __builtin_amdgcn_rcpf(t + 1.f);
}
__device__ __forceinline__ unsigned umax4(u16x8 v) {
    u32x4 c = __builtin_bit_cast(u32x4, v);
    unsigned a = c.x > c.y ? c.x : c.y;
    unsigned b = c.z > c.w ? c.z : c.w;
    return a > b ? a : b;
}

// async global->LDS, 16B per lane; LDS base must be wave-uniform
typedef __attribute__((address_space(1))) const unsigned GA;
typedef __attribute__((address_space(3))) unsigned LA;
__device__ __forceinline__ void gload_lds16(const void* g, void* l) {
    __builtin_amdgcn_global_load_lds((GA*)g, (LA*)l, 16, 0, 0);
}

// ---------------- converters ----------------
__device__ __forceinline__ void cvt4(const float* in, u16* out, int idx) {
    f32x4 v = *(const f32x4*)(in + (size_t)idx * 4);
    u16x4 o = {f2bf(v.x), f2bf(v.y), f2bf(v.z), f2bf(v.w)};
    *(u16x4*)(out + (size_t)idx * 4) = o;
}

__global__ __launch_bounds__(256) void cvt_all_kernel(const float* __restrict__ w_ih,
                                                      u16* __restrict__ w_ih_bf,
                                                      const float* __restrict__ w_hh,
                                                      u16* __restrict__ w_hh_bf,
                                                      const float* __restrict__ dec_w,
                                                      u16* __restrict__ dec_w_bf) {
    int idx = blockIdx.x * 256 + threadIdx.x;
    if (idx < NC1) {
        cvt4(w_ih, w_ih_bf, idx);
    } else if (idx < NC1 + NC2) {
        cvt4(w_hh, w_hh_bf, idx - NC1);
    } else if (idx < NC1 + NC2 + NC3) {
        cvt4(dec_w, dec_w_bf, idx - NC1 - NC2);
    }
}

__global__ __launch_bounds__(256) void cvt_bf16_kernel(const float* __restrict__ in,
                                                       u16* __restrict__ out, int n4) {
    int idx = blockIdx.x * 256 + threadIdx.x;
    if (idx < n4) cvt4(in, out, idx);
}

__global__ __launch_bounds__(256) void gather_emb_kernel(const int* __restrict__ ids,
                                                         const float* __restrict__ emb_w,
                                                         u16* __restrict__ out) {
    int m = blockIdx.x;
    int id = ids[m];
    const float* src = emb_w + (size_t)id * NIN;
    u16* dst = out + (size_t)m * NIN;
    int t = threadIdx.x;
    f32x4 v = *(const f32x4*)(src + t * 4);
    u16x4 o = {f2bf(v.x), f2bf(v.y), f2bf(v.z), f2bf(v.w)};
    *(u16x4*)(dst + t * 4) = o;
}

// ---------------- decoder GEMM (m97 staging + 2D L2 blocking per XCD) ----------------
// C[8192][10000] = ctx[8192][1024] @ dec_w[10000][1024]^T + bias
// xcd = bid&7 owns m-octet [xcd*8, xcd*8+8) x all 79 n-tiles: A-panels (2MB) L2-resident.
__global__ __launch_bounds__(256) void gemm_dec_kernel(const u16* __restrict__ A,
                                                       const u16* __restrict__ B,
                                                       float* __restrict__ C,
                                                       const float* __restrict__ bias) {
    __shared__ alignas(16) u16 Asl[128 * 32];  // linear: row stride 32 elem (64 B)
    __shared__ alignas(16) u16 Bsl[128 * 32];
    int bid = blockIdx.x;
    int xcd = bid & 7;
    int k = bid >> 3;                // 0..631
    int mt = (xcd << 3) | (k & 7);   // 0..63
    int nt = k >> 3;                 // 0..78
    int m0 = mt * 128, n0 = nt * 128;

    int t = threadIdx.x;
    int lane = t & 63, w = t >> 6;
    int wr = w >> 1, wc = w & 1;
    int l15 = lane & 15, l4 = lane >> 4;
    int rsub = lane >> 2;       // 0..15
    int kof = (lane & 3) * 8;   // element offset within 32-wide K slice

    f32x4 acc[4][4];
    f32x4 zv = {0.f, 0.f, 0.f, 0.f};
    for (int mi = 0; mi < 4; ++mi)
        for (int ni = 0; ni < 4; ++ni) acc[mi][ni] = zv;

    for (int k0 = 0; k0 < HID; k0 += 32) {
#pragma unroll
        for (int s = 0; s < 2; ++s) {
            int row = s * 64 + w * 16 + rsub;
            const u16* gA = A + (size_t)(m0 + row) * HID + k0 + kof;
            gload_lds16(gA, Asl + (s * 64 + w * 16) * 32);  // LDS base wave-uniform
            int brow = n0 + row;
            if (brow > VOC - 1) brow = VOC - 1;  // clamp; outputs guarded at write
            const u16* gB = B + (size_t)brow * HID + k0 + kof;
            gload_lds16(gB, Bsl + (s * 64 + w * 16) * 32);
        }
        __syncthreads();  // compiler drains vmcnt(0) before barrier
        bf16x8 af[4], bfr[4];
        for (int mi = 0; mi < 4; ++mi)
            af[mi] = __builtin_bit_cast(bf16x8,
                                        *(const u16x8*)(Asl + (wr * 64 + mi * 16 + l15) * 32 + l4 * 8));
        for (int ni = 0; ni < 4; ++ni)
            bfr[ni] = __builtin_bit_cast(bf16x8,
                                         *(const u16x8*)(Bsl + (wc * 64 + ni * 16 + l15) * 32 + l4 * 8));
        for (int mi = 0; mi < 4; ++mi)
            for (int ni = 0; ni < 4; ++ni)
                acc[mi][ni] = __builtin_amdgcn_mfma_f32_16x16x32_bf16(af[mi], bfr[ni], acc[mi][ni], 0, 0, 0);
        __syncthreads();
    }

    for (int mi = 0; mi < 4; ++mi)
        for (int ni = 0; ni < 4; ++ni) {
            int col = n0 + wc * 64 + ni * 16 + l15;
            if (col < VOC) {
                float bb = bias[col];
                int rbase = m0 + wr * 64 + mi * 16 + l4 * 4;
                for (int r = 0; r < 4; ++r)
                    C[(size_t)(rbase + r) * VOC + col] = acc[mi][ni][r] + bb;
            }
        }
}

// ---------------- fused recurrence + gemm1 workers (PLAIN launch, 224 blocks = 1/CU) ----------------
__global__ __launch_bounds__(256, 1) void lstm_seq_kernel(
    const float* __restrict__ c0, const u16* __restrict__ w_hh_bf, u16* __restrict__ gxT,
    const float* __restrict__ Wv, const float* __restrict__ Uv, u16* __restrict__ hb_hist,
    float* __restrict__ out_tail, float* __restrict__ part_ab, const u16* __restrict__ A_emb,
    const u16* __restrict__ w_ih_bf) {
    __shared__ alignas(16) u16 Bs[64][1024];  // recurrence: w_hh slice; workers: As2/Bs2 tiles
    __shared__ float gsm[4][32][17];
    __shared__ float c_sl[32][17];

    int blk = blockIdx.x;
    int t = threadIdx.x;
    int lane = t & 63, wave = t >> 6;
    int l15 = lane & 15, l4 = lane >> 4;

    if (blk >= NB) {
        // =========== ROLE 2: gemm1 worker ===========
        u16(*As2)[40] = (u16(*)[40])(&Bs[0][0]);
        u16(*Bs2)[40] = (u16(*)[40])((char*)(&Bs[0][0]) + 10240);
        int wr = wave >> 1, wc = wave & 1;
        for (int tau = blk - NB; tau < 2048; tau += NW) {
            int m0 = (tau >> 5) * 128;  // i-major: low i-tiles first across all workers
            int n0 = (tau & 31) * 128;
            f32x4 acc[4][4];
            f32x4 zv = {0.f, 0.f, 0.f, 0.f};
            for (int mi = 0; mi < 4; ++mi)
                for (int ni = 0; ni < 4; ++ni) acc[mi][ni] = zv;
            for (int k0 = 0; k0 < NIN; k0 += 32) {
                for (int s = 0; s < 2; ++s) {
                    int task = t + s * 256;
                    int row = task >> 2, kof = (task & 3) * 8;
                    *(u16x8*)(&As2[row][kof]) =
                        *(const u16x8*)(A_emb + (size_t)(m0 + row) * NIN + k0 + kof);
                    *(u16x8*)(&Bs2[row][kof]) =
                        *(const u16x8*)(w_ih_bf + (size_t)(n0 + row) * NIN + k0 + kof);
                }
                __syncthreads();
                bf16x8 af[4], bfr[4];
                for (int mi = 0; mi < 4; ++mi)
                    af[mi] = __builtin_bit_cast(bf16x8,
                                                *(const u16x8*)(&As2[wr * 64 + mi * 16 + l15][l4 * 8]));
                for (int ni = 0; ni < 4; ++ni)
                    bfr[ni] = __builtin_bit_cast(bf16x8,
                                                 *(const u16x8*)(&Bs2[wc * 64 + ni * 16 + l15][l4 * 8]));
                for (int mi = 0; mi < 4; ++mi)
                    for (int ni = 0; ni < 4; ++ni)
                        acc[mi][ni] =
                            __builtin_amdgcn_mfma_f32_16x16x32_bf16(af[mi], bfr[ni], acc[mi][ni], 0, 0, 0);
                __syncthreads();
            }
            // epilogue: transposed bf16 publish (write-through u64 atomics)
            for (int mi = 0; mi < 4; ++mi)
                for (int ni = 0; ni < 4; ++ni) {
                    int n = n0 + wc * 64 + ni * 16 + l15;
                    int g = n >> 10, dd = n & 1023;
                    int dblk = dd >> 4, dl = dd & 15;
                    int mbase = m0 + wr * 64 + mi * 16 + l4 * 4;
                    int i = mbase >> 5, bb2 = mbase & 31;
                    size_t idx = ((((size_t)dblk * L_SEQ + i) * 4 + g) * 16 + dl) * 32 + bb2;
                    u32 lo = (u32)f2bf(acc[mi][ni][0]) | ((u32)f2bf(acc[mi][ni][1]) << 16);
                    u32 hi = (u32)f2bf(acc[mi][ni][2]) | ((u32)f2bf(acc[mi][ni][3]) << 16);
                    u64 pk = (u64)lo | ((u64)hi << 32);
                    __hip_atomic_store((u64*)(gxT + idx), pk, __ATOMIC_RELAXED,
                                       __HIP_MEMORY_SCOPE_AGENT);
                }
        }
        return;
    }

    // =========== ROLE 1: recurrence (r9-exact + gxT sentinel poll) ===========
    int d0 = blk * DPB;
    int wm = wave & 1, wn = wave >> 1;

    for (int s = 0; s < 32; ++s) {
        int cid = t + s * 256;
        int c = cid >> 7;
        int ch = cid & 127;
        int g = c >> 4, dl = c & 15;
        u16x8 v = *(const u16x8*)(w_hh_bf + (size_t)(g * HID + d0 + dl) * HID + ch * 8);
        int chs = ch ^ (c & 7);
        *(u16x8*)(&Bs[c][chs * 8]) = v;
    }
    for (int s = t; s < 512; s += 256) {
        int b = s >> 4, dl = s & 15;
        c_sl[b][dl] = c0[b * HID + d0 + dl];
    }
    __syncthreads();

    int cA = wn * 32 + l15;
    int cB = cA + 16;
    int sw = cA & 7;
    int gA = cA >> 4, dA = cA & 15;
    int gB = cB >> 4, dB = cB & 15;

    int bb = t >> 3;
    int pr = t & 7;
    int dl0 = pr * 2;

    const u16* gxTb = gxT + (size_t)blk * ((size_t)L_SEQ * 2048) + wm * 16 + l4 * 4;

    // prologue: issue gate-bias loads for step 0 (validated at use)
    u16x4 gw0, gw1;
    {
        const u16* p0 = gxTb + gA * 512 + dA * 32;
        const u16* p1 = gxTb + gB * 512 + dB * 32;
        asm volatile("global_load_dwordx2 %0, %1, off sc0 sc1" : "=v"(gw0) : "v"(p0));
        asm volatile("global_load_dwordx2 %0, %1, off sc0 sc1" : "=v"(gw1) : "v"(p1));
    }

    for (int i = 0; i < L_SEQ; ++i) {
        const u16* hb = hb_hist + (size_t)i * (BSZ * HID);
        const u16* aptr = hb + (size_t)(wm * 16 + l15) * HID + l4 * 8;
        const u16* cp0 = gxTb + (size_t)i * 2048 + gA * 512 + dA * 32;
        const u16* cp1 = gxTb + (size_t)i * 2048 + gB * 512 + dB * 32;

        // issue all 32 A-fragment loads (bypass caches)
        u16x8 afr[32];
#pragma unroll
        for (int kk = 0; kk < 32; ++kk)
            asm volatile("global_load_dwordx4 %0, %1, off offset:%c2 sc0 sc1"
                         : "=v"(afr[kk])
                         : "v"(aptr), "n"(kk * 64));

        // consume-as-arrive poll (also drains the gw prefetch)
        f32x4 acc0 = {0.f, 0.f, 0.f, 0.f}, acc1 = {0.f, 0.f, 0.f, 0.f};
        unsigned pend = 0xFFFFFFFFu;
        for (;;) {
            asm volatile("s_waitcnt vmcnt(0)" ::: "memory");
            __builtin_amdgcn_sched_barrier(0);
            unsigned done = 0;
#pragma unroll
            for (int kk = 0; kk < 32; ++kk) {
                if (pend & (1u << kk)) {
                    if (__ballot(umax4(afr[kk]) == SENT) == 0) {
                        bf16x8 af = __builtin_bit_cast(bf16x8, afr[kk]);
                        int ch = kk * 4 + l4;
                        bf16x8 b0 = __builtin_bit_cast(bf16x8, *(const u16x8*)(&Bs[cA][(ch ^ sw) * 8]));
                        bf16x8 b1 = __builtin_bit_cast(bf16x8, *(const u16x8*)(&Bs[cB][(ch ^ sw) * 8]));
                        acc0 = __builtin_amdgcn_mfma_f32_16x16x32_bf16(af, b0, acc0, 0, 0, 0);
                        acc1 = __builtin_amdgcn_mfma_f32_16x16x32_bf16(af, b1, acc1, 0, 0, 0);
                        done |= 1u << kk;
                    }
                }
            }
            pend &= ~done;
            if (!pend) break;
#pragma unroll
            for (int kk = 0; kk < 32; ++kk)
                if (pend & (1u << kk))
                    asm volatile("global_load_dwordx4 %0, %1, off offset:%c2 sc0 sc1"
                                 : "=v"(afr[kk])
                                 : "v"(aptr), "n"(kk * 64));
            __builtin_amdgcn_s_sleep(1);
        }
        __builtin_amdgcn_sched_barrier(0);

        // validate prefetched gate biases (sentinel poll; workers run far ahead)
        for (;;) {
            u32x2 w0 = __builtin_bit_cast(u32x2, gw0);
            u32x2 w1 = __builtin_bit_cast(u32x2, gw1);
            if (__ballot(w0.x == SENT || w0.y == SENT || w1.x == SENT || w1.y == SENT) == 0) break;
            __builtin_amdgcn_s_sleep(4);
            asm volatile("global_load_dwordx2 %0, %1, off sc0 sc1" : "=v"(gw0) : "v"(cp0));
            asm volatile("global_load_dwordx2 %0, %1, off sc0 sc1" : "=v"(gw1) : "v"(cp1));
            asm volatile("s_waitcnt vmcnt(0)" ::: "memory");
            __builtin_amdgcn_sched_barrier(0);
        }

#pragma unroll
        for (int r = 0; r < 4; ++r) {
            int m = wm * 16 + l4 * 4 + r;
            gsm[gA][m][dA] = acc0[r] + BF2F(gw0[r]);
            gsm[gB][m][dB] = acc1[r] + BF2F(gw1[r]);
        }
        __syncthreads();

        // cell update: thread handles (bb, dl0) and (bb, dl0+1); publish h ASAP
        u16* hb_next = hb_hist + (size_t)(i + 1) * (BSZ * HID);
        float hn01[2];
#pragma unroll
        for (int q = 0; q < 2; ++q) {
            int dl = dl0 + q;
            float ig = gsm[0][bb][dl], fg = gsm[1][bb][dl];
            float gg = gsm[2][bb][dl], og = gsm[3][bb][dl];
            float cn = fast_sigm(fg) * c_sl[bb][dl] + fast_sigm(ig) * fast_tanh(gg);
            float hn = fast_sigm(og) * fast_tanh(cn);
            c_sl[bb][dl] = cn;
            hn01[q] = hn;
        }
        unsigned pk = (unsigned)f2bf(hn01[0]) | ((unsigned)f2bf(hn01[1]) << 16);
        __hip_atomic_store((unsigned*)(hb_next + bb * HID + d0 + dl0), pk,
                           __ATOMIC_RELAXED, __HIP_MEMORY_SCOPE_AGENT);
        if (i == L_SEQ - 1) {
            f32x2 hv = {hn01[0], hn01[1]};
            *(f32x2*)(out_tail + (size_t)bb * HID + d0 + dl0) = hv;
        }
        float pa = hn01[0] * Wv[d0 + dl0] + hn01[1] * Wv[d0 + dl0 + 1];
        float pb = hn01[0] * Uv[d0 + dl0] + hn01[1] * Uv[d0 + dl0 + 1];
        pa += __shfl_xor(pa, 1); pb += __shfl_xor(pb, 1);
        pa += __shfl_xor(pa, 2); pb += __shfl_xor(pb, 2);
        pa += __shfl_xor(pa, 4); pb += __shfl_xor(pb, 4);
        if (pr == 0) {
            f32x2 pv = {pa, pb};
            *(f32x2*)(part_ab + (((size_t)i * NB + blk) * BSZ + bb) * 2) = pv;
        }

        // prefetch gate biases for the NEXT step (land during next h-poll)
        {
            int inx = (i + 1 < L_SEQ) ? i + 1 : i;
            const u16* np0 = gxTb + (size_t)inx * 2048 + gA * 512 + dA * 32;
            const u16* np1 = gxTb + (size_t)inx * 2048 + gB * 512 + dB * 32;
            asm volatile("global_load_dwordx2 %0, %1, off sc0 sc1" : "=v"(gw0) : "v"(np0));
            asm volatile("global_load_dwordx2 %0, %1, off sc0 sc1" : "=v"(gw1) : "v"(np1));
        }
    }

    for (int s = t; s < 512; s += 256) {
        int b2 = s >> 4, dl = s & 15;
        out_tail[(size_t)BSZ * HID + b2 * HID + d0 + dl] = c_sl[b2][dl];
    }
}

// ---------------- reduce a/b partials: a[i][b] = sum_blk part ----------------
__global__ __launch_bounds__(256) void reduce_ab_kernel(const float* __restrict__ part_ab,
                                                        float* __restrict__ a_arr,
                                                        float* __restrict__ b_arr) {
    int i = blockIdx.x;
    int t = threadIdx.x;
    int b = t & 31, q = t >> 5;
    float sa = 0.f, sb = 0.f;
    for (int j = 0; j < 8; ++j) {
        int blk = q * 8 + j;
        f32x2 v = *(const f32x2*)(part_ab + (((size_t)i * NB + blk) * BSZ + b) * 2);
        sa += v.x;
        sb += v.y;
    }
    __shared__ float ra[8][32], rb[8][32];
    ra[q][b] = sa;
    rb[q][b] = sb;
    __syncthreads();
    if (q == 0) {
        for (int j = 1; j < 8; ++j) { sa += ra[j][b]; sb += rb[j][b]; }
        a_arr[i * BSZ + b] = sa;
        b_arr[i * BSZ + b] = sb;
    }
}

// ---------------- attention: 16 queries per block, one batch per block.y (bf16 hist) ----------------
__global__ __launch_bounds__(256) void attn_kernel(const float* __restrict__ a_arr,
                                                   const float* __restrict__ b_arr,
                                                   const u16* __restrict__ hb_hist,
                                                   u16* __restrict__ ctx_bf) {
    int b = blockIdx.y;
    int i0 = blockIdx.x * 16;
    int t = threadIdx.x;
    __shared__ float att[16][256];
    __shared__ float red[256];

    float bt = b_arr[t * BSZ + b];
    for (int q = 0; q < 16; ++q) {
        int iq = i0 + q;
        att[q][t] = (t <= iq) ? tanhf(a_arr[iq * BSZ + b] + bt) : -INFINITY;
    }
    __syncthreads();
    for (int q = 0; q < 16; ++q) {
        int iq = i0 + q;
        red[t] = att[q][t];
        __syncthreads();
        for (int s = 128; s > 0; s >>= 1) {
            if (t < s) red[t] = fmaxf(red[t], red[t + s]);
            __syncthreads();
        }
        float m = red[0];
        __syncthreads();
        float e = (t <= iq) ? __expf(att[q][t] - m) : 0.f;
        red[t] = e;
        __syncthreads();
        for (int s = 128; s > 0; s >>= 1) {
            if (t < s) red[t] += red[t + s];
            __syncthreads();
        }
        float sum = red[0];
        __syncthreads();
        att[q][t] = e / sum;
        __syncthreads();
    }

    int hc = t * 4;
    f32x4 accq[16];
    f32x4 zv = {0.f, 0.f, 0.f, 0.f};
    for (int q = 0; q < 16; ++q) accq[q] = zv;
    int imax = i0 + 15;
    for (int t2 = 0; t2 <= imax; ++t2) {
        u16x4 hq = *(const u16x4*)(hb_hist + (size_t)(t2 + 1) * (BSZ * HID) + (size_t)b * HID + hc);
        f32x4 hv = {BF2F(hq.x), BF2F(hq.y), BF2F(hq.z), BF2F(hq.w)};
        for (int q = 0; q < 16; ++q) accq[q] += hv * att[q][t2];
    }
    for (int q = 0; q < 16; ++q) {
        size_t row = (size_t)(i0 + q) * BSZ + b;
        u16x4 o = {f2bf(accq[q].x), f2bf(accq[q].y), f2bf(accq[q].z), f2bf(accq[q].w)};
        *(u16x4*)(ctx_bf + row * HID + hc) = o;
    }
}

// ---------------- in-place log_softmax over rows of [8192][10000], register-cached ----------------
__global__ __launch_bounds__(256) void logsoftmax_kernel(float* __restrict__ x, int V) {
    int row = blockIdx.x;
    float* p = x + (size_t)row * V;
    __shared__ float red[256];
    int t = threadIdx.x;
    float frag[40];
    float m = -INFINITY;
#pragma unroll
    for (int k = 0; k < 40; ++k) {
        int j = t + k * 256;
        if (j < VOC) {
            frag[k] = p[j];
            m = fmaxf(m, frag[k]);
        }
    }
    red[t] = m;
    __syncthreads();
    for (int s = 128; s > 0; s >>= 1) {
        if (t < s) red[t] = fmaxf(red[t], red[t + s]);
        __syncthreads();
    }
    m = red[0];
    __syncthreads();
    float sum = 0.f;
#pragma unroll
    for (int k = 0; k < 40; ++k) {
        int j = t + k * 256;
        if (j < VOC) sum += __expf(frag[k] - m);
    }
    red[t] = sum;
    __syncthreads();
    for (int s = 128; s > 0; s >>= 1) {
        if (t < s) red[t] += red[t + s];
        __syncthreads();
    }
    float lse = m + logf(red[0]);
#pragma unroll
    for (int k = 0; k < 40; ++k) {
        int j = t + k * 256;
        if (j < VOC) p[j] = frag[k] - lse;
    }
}

extern "C" void kernel_launch(void* const* d_in, const int* in_sizes, int n_in,
                              void* d_out, int out_size, void* d_ws, size_t ws_size,
                              hipStream_t stream) {
    const int* ids = (const int*)d_in[0];
    const float* h0 = (const float*)d_in[1];
    const float* c0 = (const float*)d_in[2];
    const float* emb_w = (const float*)d_in[3];
    const float* w_ih = (const float*)d_in[4];
    const float* w_hh = (const float*)d_in[5];
    const float* dec_w = (const float*)d_in[6];
    const float* dec_b = (const float*)d_in[7];
    const float* Wv = (const float*)d_in[8];
    const float* Uv = (const float*)d_in[9];

    char* p = (char*)d_ws;
    auto alloc = [&](size_t bytes) {
        void* r = (void*)p;
        p += (bytes + 255) & ~(size_t)255;
        return r;
    };
    // ws total ~89 MiB
    u16* w_ih_bf = (u16*)alloc((size_t)G4 * NIN * 2);                 // 8 MiB
    u16* w_hh_bf = (u16*)alloc((size_t)G4 * HID * 2);                 // 8 MiB
    u16* dec_w_bf = (u16*)alloc((size_t)VOC * HID * 2);               // 20 MiB
    u16* hb_hist = (u16*)alloc((size_t)(L_SEQ + 1) * BSZ * HID * 2);  // 16.84 MiB (dedicated)
    u16* A_emb = (u16*)alloc((size_t)MROWS * NIN * 2);                // 16 MiB (dedicated)
    u16* ctx_bf = (u16*)alloc((size_t)MROWS * HID * 2);               // 16 MiB
    float* part_ab = (float*)alloc((size_t)L_SEQ * NB * BSZ * 2 * 4); // 4 MiB
    float* a_arr = (float*)alloc((size_t)L_SEQ * BSZ * 4);
    float* b_arr = (float*)alloc((size_t)L_SEQ * BSZ * 4);

    float* out = (float*)d_out;
    u16* gxT = (u16*)d_out;  // bf16 transposed gx: first 64 MiB of d_out (dead before logits)
    float* out_tail = out + (size_t)MROWS * VOC;

    // phase 1: conversions + gathers (pre-kernels; kernel-boundary coherence for worker inputs)
    cvt_all_kernel<<<(NC1 + NC2 + NC3 + 255) / 256, 256, 0, stream>>>(w_ih, w_ih_bf, w_hh,
                                                                      w_hh_bf, dec_w, dec_w_bf);
    gather_emb_kernel<<<MROWS, 256, 0, stream>>>(ids, emb_w, A_emb);

    // phase 2: sentinel fills — gxT (all), hb_hist slots 1..256; h(0) into slot 0
    hipMemsetAsync(gxT, 0xFF, (size_t)MROWS * G4 * 2, stream);
    hipMemsetAsync(hb_hist + (size_t)BSZ * HID, 0xFF, (size_t)L_SEQ * BSZ * HID * 2, stream);
    cvt_bf16_kernel<<<BSZ * HID / 1024, 256, 0, stream>>>(h0, hb_hist, BSZ * HID / 4);

    // phase 3: fused recurrence + gemm1 — PLAIN launch (no grid barrier in kernel)
    lstm_seq_kernel<<<dim3(NB + NW), dim3(256), 0, stream>>>(c0, w_hh_bf, gxT, Wv, Uv, hb_hist,
                                                             out_tail, part_ab, A_emb, w_ih_bf);

    // phase 4: tail pipeline
    reduce_ab_kernel<<<L_SEQ, 256, 0, stream>>>(part_ab, a_arr, b_arr);
    attn_kernel<<<dim3(L_SEQ / 16, BSZ), 256, 0, stream>>>(a_arr, b_arr, hb_hist, ctx_bf);
    gemm_dec_kernel<<<dim3(64 * NT_N), 256, 0, stream>>>(ctx_bf, dec_w_bf, out, dec_b);
    logsoftmax_kernel<<<MROWS, 256, 0, stream>>>(out, VOC);
}